// Round 18
// baseline (259.109 us; speedup 1.0000x reference)
//
#include <hip/hip_runtime.h>
#include <math.h>

typedef __bf16 bf16;
typedef __bf16 bf16x8 __attribute__((ext_vector_type(8)));
typedef __bf16 bf16x4 __attribute__((ext_vector_type(4)));
typedef float  f32x4  __attribute__((ext_vector_type(4)));

#define HW        16384      // 128*128
#define OUT_ELEMS 4194304    // 4*64*128*128

// padded xm: [b][m][yp=142][xp=142][c=64], pixel (y,x) at (y+7, x+7)
#define XM_ROW    (142 * 64)
#define XM_PLANE  (142 * XM_ROW)          // 1,290,496 el
// padded cat: [b][yp=130][xp=130][ch=256], pixel (y,x) at (y+1, x+1)
#define CAT_ROW   (130 * 256)
#define CAT_PLANE (130 * CAT_ROW)         // 4,326,400 el

// LDS pixel stride for k_final (64 payload + 8 pad -> 144 B)
#define LPX 72

// -------- mask conv stage 1: partial logits over 8-channel groups ------------
// part aliases the cat_p region (dead before k_branch writes cat_p).
__global__ void k_mask1(const float* __restrict__ x, const float* __restrict__ mw,
                        float* __restrict__ part) {
  int y = blockIdx.x, b = blockIdx.y, cg = blockIdx.z;
  int tx = threadIdx.x;      // 0..127
  float a0 = 0.f, a1 = 0.f, a2 = 0.f;
#pragma unroll
  for (int ci = 0; ci < 8; ++ci) {
    int c = cg * 8 + ci;
    const float* xp = x + ((size_t)(b * 64 + c)) * HW;
    const float* w0 = mw + (0 * 64 + c) * 9;
    const float* w1 = mw + (1 * 64 + c) * 9;
    const float* w2 = mw + (2 * 64 + c) * 9;
#pragma unroll
    for (int ky = 0; ky < 3; ++ky) {
      int yy = y + ky - 1;
      if ((unsigned)yy >= 128u) continue;
#pragma unroll
      for (int kx = 0; kx < 3; ++kx) {
        int xx = tx + kx - 1;
        if ((unsigned)xx >= 128u) continue;
        float xv = xp[yy * 128 + xx];
        a0 += xv * w0[ky * 3 + kx];
        a1 += xv * w1[ky * 3 + kx];
        a2 += xv * w2[ky * 3 + kx];
      }
    }
  }
  size_t base = (size_t)((b * 8 + cg) * 3) * HW + y * 128 + tx;
  part[base]          = a0;
  part[base + HW]     = a1;
  part[base + 2 * HW] = a2;
}

// -------- xm repack + FOLDED weight transforms + FOLDED mask softmax ---------
__global__ void k_xmt(const float* __restrict__ x, const float* __restrict__ part,
                      const float* __restrict__ mb, float* __restrict__ masks,
                      bf16* __restrict__ xm_p,
                      const float* __restrict__ kern, const float* __restrict__ w2,
                      bf16* __restrict__ kern_t, bf16* __restrict__ w2_t) {
  int yp = blockIdx.x;  // 0..141 padded row
  int m = blockIdx.y, b = blockIdx.z;
  int t = threadIdx.x;  // 256

  // ---- folded weight transforms: 1704 blocks x 256 thr x 2 iters -----------
  {
    const int NK  = 442368;            // kern_t elements
    const int NW2 = 147456;            // w2_t elements
    int bid2 = yp + 142 * (m + 3 * b); // 0..1703
#pragma unroll
    for (int it = 0; it < 2; ++it) {
      int idx = (bid2 + it * 1704) * 256 + t;
      if (idx < NK) {
        int j    = idx & 7;
        int lane = (idx >> 3) & 63;
        int km   = (idx >> 9) & 7;     // kci = km&1, mt = km>>1
        int tap  = (idx >> 12) % 9;
        int bm   = idx / 36864;
        int o = (km >> 1) * 16 + (lane & 15);
        int c = (km & 1) * 32 + (lane >> 4) * 8 + j;
        kern_t[idx] = (bf16)kern[(((bm * 64 + o) * 64 + c) * 9) + tap];
      } else if (idx < NK + NW2) {
        int j = idx - NK;
        int j8   = j & 7;
        int lane = (j >> 3) & 63;
        int km   = (j >> 9) & 7;
        int cq   = (j >> 12) & 3;
        int tap  = j >> 14;            // 0..8
        int oc = (km >> 1) * 16 + (lane & 15);
        int ch = cq * 64 + (km & 1) * 32 + (lane >> 4) * 8 + j8;
        w2_t[j] = (bf16)w2[(oc * 256 + ch) * 9 + tap];
      }
    }
  }

  bf16* prow = xm_p + (size_t)(b * 3 + m) * XM_PLANE + (size_t)yp * XM_ROW;
  bf16x8 z = {};
  if (yp < 7 || yp >= 135) {          // full halo row: 142*64/8 = 1136 chunks
#pragma unroll
    for (int i = 0; i < 5; ++i) {
      int u = i * 256 + t;
      if (u < 1136) ((bf16x8*)prow)[u] = z;
    }
    return;
  }
  // side halo: 7 px * 64c = 448 el = 56 chunks each side
  if (t < 56) ((bf16x8*)prow)[t] = z;
  else if (t < 112) ((bf16x8*)(prow + 135 * 64))[t - 56] = z;

  int y = yp - 7;
  __shared__ float tile[64 * 130];
  __shared__ float mrow_s[128];
#pragma unroll
  for (int i = 0; i < 32; ++i) {
    int u = i * 256 + t;           // 0..8191
    int c = u >> 7, xx = u & 127;
    tile[c * 130 + xx] = x[((size_t)(b * 64 + c)) * HW + y * 128 + xx];
  }
  // folded mask softmax: reduce 8 groups + bias + softmax (tx<128)
  if (t < 128) {
    float a0 = mb[0], a1 = mb[1], a2 = mb[2];
    int off = y * 128 + t;
#pragma unroll
    for (int cg = 0; cg < 8; ++cg) {
      size_t base = (size_t)((b * 8 + cg) * 3) * HW + off;
      a0 += part[base];
      a1 += part[base + HW];
      a2 += part[base + 2 * HW];
    }
    float mx = fmaxf(a0, fmaxf(a1, a2));
    float e0 = __expf(a0 - mx), e1 = __expf(a1 - mx), e2 = __expf(a2 - mx);
    float inv = 1.0f / (e0 + e1 + e2);
    float v0 = e0 * inv, v1 = e1 * inv, v2 = e2 * inv;
    mrow_s[t] = (m == 0) ? v0 : (m == 1) ? v1 : v2;
    if (m == 0) {                       // one writer per (y,b): all 3 rows
      size_t mbase = ((size_t)b * 3) * HW + off;
      masks[mbase]          = v0;
      masks[mbase + HW]     = v1;
      masks[mbase + 2 * HW] = v2;
    }
  }
  __syncthreads();
  bf16* orow = prow + 7 * 64;
  // vectorized repack: thread -> (cg = 8-ch group, xx = pixel); bf16x8 store
#pragma unroll
  for (int i = 0; i < 4; ++i) {
    int u = i * 256 + t;           // 0..1023
    int cg = u & 7, xx = u >> 3;
    float mv = mrow_s[xx];
    bf16x8 v;
#pragma unroll
    for (int j = 0; j < 8; ++j)
      v[j] = (bf16)(tile[(cg * 8 + j) * 130 + xx] * mv);
    *(bf16x8*)(orow + xx * 64 + cg * 8) = v;
  }
}

// ------- branch convs: 1-WAVE workgroups, wave-autonomous, swizzled LDS ------
// r17: conflicts=0 but occupancy stuck at 2 blocks/CU (granule theory dead).
// Waves share NOTHING (no barriers, private strips) -> dissolve 4-wave blocks
// into 64-thread workgroups: 8192 blocks, LDS 11,776 B each -> residency cap
// becomes ~13 waves/CU (LDS) instead of 2x4=8. Same code per wave otherwise.
__global__ __launch_bounds__(64) void k_branch(const bf16* __restrict__ xm_p,
                                               const bf16* __restrict__ kern_t,
                                               bf16* __restrict__ cat_p) {
  __shared__ bf16 sb[2][46 * 64];   // dbuf x 5,888 B = 11,776 B (1 wave)
  int bid = blockIdx.x;             // 0..8191
  int lane = threadIdx.x;           // 0..63
  // ---- folded halo zeroing: 66,048 items over 8192x64 threads --------------
  {
    int id = bid * 64 + lane;
    if (id < 4 * 16512) {
      int plane = id / 16512, j = id % 16512;
      bf16* base = cat_p + (size_t)plane * CAT_PLANE;
      bf16x8 zv = {};
      if (j < 8320) {                   // rows 0 and 129, full 130 px
        int row = (j / 4160) * 129;
        int off = (j % 4160) * 8;
        *(bf16x8*)(base + (size_t)row * CAT_ROW + off) = zv;
      } else {                          // rows 1..128, cols 0 and 129
        int k = j - 8320;
        int row = 1 + (k >> 6);
        int idx2 = k & 63;
        int col = (idx2 >> 5) * 129;
        int ch8 = (idx2 & 31) * 8;
        *(bf16x8*)(base + (size_t)row * CAT_ROW + col * 256 + ch8) = zv;
      }
    }
  }
  int wq   = bid & 3;           // px quarter (siblings have consecutive bids)
  int rest = bid >> 2;          // 0..2047
  int xcd = rest & 7;
  int i   = rest >> 3;          // 0..255
  int b   = xcd >> 1;
  int di  = ((xcd & 1) << 1) | (i & 1);
  int y   = i >> 1;             // 0..127
  int d   = 1 + 2 * di;         // 1,3,5,7
  int lanelo = lane & 15;
  int quad = lane >> 4;

  const bf16* plane0 = xm_p + (size_t)(b * 3) * XM_PLANE;
  const bf16* wb0    = kern_t + (size_t)(b * 27) * 4096 + lane * 8;
  const int gp0 = wq * 32 + 7 - d;     // leftmost staged padded-px of this wave

  bf16* mysb0 = &sb[0][0];
  bf16* mysb1 = &sb[1][0];

  bf16x8 sreg[6];   // 46px x 64ch = 368 chunks of 16B (guard u<368)
  // swizzled LDS element offset for (px, slot): px*64 + ((slot ^ (px&7))<<3)
  // prologue: phase 0 (m=0,ky=0) -> buf0; issue phase 1 (m=0,ky=1) loads
  {
    const bf16* s0 = plane0 + (size_t)(y + 7 - d) * XM_ROW + gp0 * 64;
#pragma unroll
    for (int r = 0; r < 6; ++r) {
      int u = r * 64 + lane;
      if (u < 368) sreg[r] = *(const bf16x8*)(s0 + u * 8);
    }
#pragma unroll
    for (int r = 0; r < 6; ++r) {
      int u = r * 64 + lane;
      if (u < 368) {
        int px = u >> 3, sl = u & 7;
        *(bf16x8*)(mysb0 + px * 64 + ((sl ^ (px & 7)) << 3)) = sreg[r];
      }
    }
    const bf16* s1 = plane0 + (size_t)(y + 7) * XM_ROW + gp0 * 64;
#pragma unroll
    for (int r = 0; r < 6; ++r) {
      int u = r * 64 + lane;
      if (u < 368) sreg[r] = *(const bf16x8*)(s1 + u * 8);
    }
  }

  f32x4 acc[4][2] = {};

#pragma unroll
  for (int p = 0; p < 9; ++p) {
    int m = p / 3, ky = p % 3;
    // A-frags: 3 kx x 2 kci x 4 mt, each one coalesced 1KB wave-load
    bf16x8 areg[3][2][4];
    const bf16* wtap = wb0 + (size_t)(m * 9 + ky * 3) * 4096;
#pragma unroll
    for (int kx = 0; kx < 3; ++kx)
#pragma unroll
      for (int kci = 0; kci < 2; ++kci)
#pragma unroll
        for (int mt = 0; mt < 4; ++mt)
          areg[kx][kci][mt] = *(const bf16x8*)(wtap + kx * 4096 + (mt * 2 + kci) * 512);

    // write phase p+1 (loaded at p-1) into the other private buffer
    if (p < 8) {
      bf16* wbuf = ((p + 1) & 1) ? mysb1 : mysb0;
#pragma unroll
      for (int r = 0; r < 6; ++r) {
        int u = r * 64 + lane;
        if (u < 368) {
          int px = u >> 3, sl = u & 7;
          *(bf16x8*)(wbuf + px * 64 + ((sl ^ (px & 7)) << 3)) = sreg[r];
        }
      }
    }
    // issue staging loads for phase p+2
    if (p < 7) {
      int pn = p + 2;
      int mn = pn / 3, kyn = pn % 3;
      const bf16* sn = plane0 + (size_t)mn * XM_PLANE
                     + (size_t)(y + 7 + d * (kyn - 1)) * XM_ROW + gp0 * 64;
#pragma unroll
      for (int r = 0; r < 6; ++r) {
        int u = r * 64 + lane;
        if (u < 368) sreg[r] = *(const bf16x8*)(sn + u * 8);
      }
    }
    // compute from private buf[p&1]; local px = lanelo + d*kx (+ nt*16)
    const bf16* rbuf = (p & 1) ? mysb1 : mysb0;
#pragma unroll
    for (int kx = 0; kx < 3; ++kx) {
      int lpx0 = lanelo + d * kx;
      int p7   = lpx0 & 7;             // (lpx0+nt*16)&7 == lpx0&7
#pragma unroll
      for (int kci = 0; kci < 2; ++kci) {
        int swsl = ((quad + 4 * kci) ^ p7) << 3;
        bf16x8 bv[2];
#pragma unroll
        for (int nt = 0; nt < 2; ++nt)
          bv[nt] = *(const bf16x8*)(rbuf + (lpx0 + nt * 16) * 64 + swsl);
        __builtin_amdgcn_s_setprio(1);
#pragma unroll
        for (int mt = 0; mt < 4; ++mt)
#pragma unroll
          for (int nt = 0; nt < 2; ++nt)
            acc[mt][nt] = __builtin_amdgcn_mfma_f32_16x16x32_bf16(areg[kx][kci][mt], bv[nt], acc[mt][nt], 0, 0, 0);
        __builtin_amdgcn_s_setprio(0);
      }
    }
  }

  // epilogue: cat_p[b][y+1][px+1][di*64 + oc]
  bf16* cp = cat_p + (size_t)b * CAT_PLANE + (size_t)(y + 1) * CAT_ROW + di * 64;
#pragma unroll
  for (int mt = 0; mt < 4; ++mt) {
#pragma unroll
    for (int nt = 0; nt < 2; ++nt) {
      int px = wq * 32 + nt * 16 + lanelo;
      bf16x4 v;
#pragma unroll
      for (int r = 0; r < 4; ++r) v[r] = (bf16)acc[mt][nt][r];
      *(bf16x4*)(cp + (size_t)(px + 1) * 256 + (mt * 16 + quad * 4)) = v;
    }
  }
}

// ------- final conv + bias + BN + ReLU: 1-WAVE workgroups --------------------
// Same dissolution: 2048 blocks x 64 thr, LDS 11,520 B/block.
__global__ __launch_bounds__(64) void k_final(const bf16* __restrict__ cat_p,
                                              const bf16* __restrict__ w2_t,
                                              const float* __restrict__ cb,
                                              const float* __restrict__ gamma,
                                              const float* __restrict__ beta,
                                              const float* __restrict__ mean,
                                              const float* __restrict__ var,
                                              float* __restrict__ out) {
  __shared__ bf16 sb[2][40 * LPX];      // dbuf x 5,760 B = 11,520 B (1 wave)
  int bid = blockIdx.x;                 // 0..2047
  int lane = threadIdx.x;               // 0..63
  int wq   = bid & 3;           // px quarter
  int rest = bid >> 2;          // 0..511
  int xcd = rest & 7;
  int b   = xcd >> 1;
  int y   = ((rest >> 3) << 1) | (xcd & 1);   // 0..127
  int lanelo = lane & 15;
  int quad = lane >> 4;

  const bf16* cb2 = cat_p + (size_t)b * CAT_PLANE + (size_t)(wq * 32) * 256;
  const bf16* wb0 = w2_t + lane * 8;

  bf16* mysb0 = &sb[0][0];
  bf16* mysb1 = &sb[1][0];

  bf16x8 sreg[5];   // 40px x 64ch = 320 chunks of 16B = 5 per lane
  // prologue: phase 0 (cq=0,ky=0) -> buf0; issue phase 1 (cq=0,ky=1) loads
  {
    const bf16* s0 = cb2 + (size_t)y * CAT_ROW;
#pragma unroll
    for (int r = 0; r < 5; ++r) {
      int u = r * 64 + lane;
      sreg[r] = *(const bf16x8*)(s0 + (u >> 3) * 256 + (u & 7) * 8);
    }
#pragma unroll
    for (int r = 0; r < 5; ++r) {
      int u = r * 64 + lane;
      *(bf16x8*)(mysb0 + (u >> 3) * LPX + (u & 7) * 8) = sreg[r];
    }
    const bf16* s1 = cb2 + (size_t)(y + 1) * CAT_ROW;
#pragma unroll
    for (int r = 0; r < 5; ++r) {
      int u = r * 64 + lane;
      sreg[r] = *(const bf16x8*)(s1 + (u >> 3) * 256 + (u & 7) * 8);
    }
  }

  f32x4 acc[4][2] = {};

#pragma unroll
  for (int p = 0; p < 12; ++p) {
    int cq = p / 3, ky = p % 3;
    // A-frags: 3 kx x 2 kci x 4 mt, each one coalesced 1KB wave-load
    bf16x8 areg[3][2][4];
#pragma unroll
    for (int kx = 0; kx < 3; ++kx) {
      const bf16* wt = wb0 + (size_t)(((ky * 3 + kx) * 4 + cq) * 8) * 512;
#pragma unroll
      for (int kci = 0; kci < 2; ++kci)
#pragma unroll
        for (int mt = 0; mt < 4; ++mt)
          areg[kx][kci][mt] = *(const bf16x8*)(wt + (mt * 2 + kci) * 512);
    }

    // write phase p+1 (loaded at p-1) into the other private buffer
    if (p < 11) {
      bf16* wbuf = ((p + 1) & 1) ? mysb1 : mysb0;
#pragma unroll
      for (int r = 0; r < 5; ++r) {
        int u = r * 64 + lane;
        *(bf16x8*)(wbuf + (u >> 3) * LPX + (u & 7) * 8) = sreg[r];
      }
    }
    // issue staging loads for phase p+2
    if (p < 10) {
      int pn = p + 2;
      int cqn = pn / 3, kyn = pn % 3;
      const bf16* sn = cb2 + (size_t)(y + kyn) * CAT_ROW + cqn * 64;
#pragma unroll
      for (int r = 0; r < 5; ++r) {
        int u = r * 64 + lane;
        sreg[r] = *(const bf16x8*)(sn + (u >> 3) * 256 + (u & 7) * 8);
      }
    }
    // compute from private buf[p&1]; local px = lanelo + kx (+ nt*16)
    const bf16* rbuf = (p & 1) ? mysb1 : mysb0;
#pragma unroll
    for (int kx = 0; kx < 3; ++kx) {
      int lpx0 = lanelo + kx;
#pragma unroll
      for (int kci = 0; kci < 2; ++kci) {
        bf16x8 bv[2];
#pragma unroll
        for (int nt = 0; nt < 2; ++nt)
          bv[nt] = *(const bf16x8*)(rbuf + (lpx0 + nt * 16) * LPX + quad * 8 + kci * 32);
        __builtin_amdgcn_s_setprio(1);
#pragma unroll
        for (int mt = 0; mt < 4; ++mt)
#pragma unroll
          for (int nt = 0; nt < 2; ++nt)
            acc[mt][nt] = __builtin_amdgcn_mfma_f32_16x16x32_bf16(areg[kx][kci][mt], bv[nt], acc[mt][nt], 0, 0, 0);
        __builtin_amdgcn_s_setprio(0);
      }
    }
  }

  // epilogue: bias + BN + ReLU -> out[b][oc][y][px]
#pragma unroll
  for (int mt = 0; mt < 4; ++mt) {
#pragma unroll
    for (int nt = 0; nt < 2; ++nt) {
      int px = wq * 32 + nt * 16 + lanelo;
#pragma unroll
      for (int r = 0; r < 4; ++r) {
        int oc = mt * 16 + quad * 4 + r;
        float inv = gamma[oc] * rsqrtf(var[oc] + 1e-5f);
        float v = (acc[mt][nt][r] + cb[oc]) * inv + beta[oc] - mean[oc] * inv;
        out[((size_t)(b * 64 + oc)) * HW + y * 128 + px] = fmaxf(v, 0.0f);
      }
    }
  }
}

extern "C" void kernel_launch(void* const* d_in, const int* in_sizes, int n_in,
                              void* d_out, int out_size, void* d_ws, size_t ws_size,
                              hipStream_t stream) {
  const float* x     = (const float*)d_in[0];
  const float* kern  = (const float*)d_in[1];
  const float* mw    = (const float*)d_in[2];
  const float* mb    = (const float*)d_in[3];
  const float* w2    = (const float*)d_in[4];
  const float* cb    = (const float*)d_in[5];
  const float* gamma = (const float*)d_in[6];
  const float* beta  = (const float*)d_in[7];
  const float* mean  = (const float*)d_in[8];
  const float* var   = (const float*)d_in[9];

  float* out   = (float*)d_out;
  float* masks = out + OUT_ELEMS;

  char* ws = (char*)d_ws;
  bf16* xm_p   = (bf16*)(ws);              // 30,971,904 B
  bf16* cat_p  = (bf16*)(ws + 30971904);   // 34,611,200 B (ends 65,583,104)
  bf16* kern_t = (bf16*)(ws + 65583104);   // 884,736 B
  bf16* w2_t   = (bf16*)(ws + 66467840);   // 294,912 B -> total 66,762,752 B
  // mask partials alias CAT_P region (dead before k_branch touches cat_p)
  float* part  = (float*)(ws + 30971904);  // 6,291,456 B < cat_p size

  k_mask1<<<dim3(128, 4, 8), 128, 0, stream>>>(x, mw, part);
  k_xmt<<<dim3(142, 3, 4), 256, 0, stream>>>(x, part, mb, masks, xm_p, kern, w2, kern_t, w2_t);
  k_branch<<<8192, 64, 0, stream>>>(xm_p, kern_t, cat_p);
  k_final<<<2048, 64, 0, stream>>>(cat_p, w2_t, cb, gamma, beta, mean, var, out);
}

// Round 19
// 227.754 us; speedup vs baseline: 1.1377x; 1.1377x over previous
//
#include <hip/hip_runtime.h>
#include <math.h>

typedef __bf16 bf16;
typedef __bf16 bf16x8 __attribute__((ext_vector_type(8)));
typedef __bf16 bf16x4 __attribute__((ext_vector_type(4)));
typedef float  f32x4  __attribute__((ext_vector_type(4)));

#define HW        16384      // 128*128
#define OUT_ELEMS 4194304    // 4*64*128*128

// padded xm: [b][m][yp=142][xp=142][c=64], pixel (y,x) at (y+7, x+7)
#define XM_ROW    (142 * 64)
#define XM_PLANE  (142 * XM_ROW)          // 1,290,496 el
// padded cat: [b][yp=130][xp=130][ch=256], pixel (y,x) at (y+1, x+1)
#define CAT_ROW   (130 * 256)
#define CAT_PLANE (130 * CAT_ROW)         // 4,326,400 el

// LDS pixel stride for k_final (64 payload + 8 pad -> 144 B)
#define LPX 72

// -------- mask conv stage 1: partial logits over 8-channel groups ------------
// part aliases the cat_p region (dead before k_branch writes cat_p).
__global__ void k_mask1(const float* __restrict__ x, const float* __restrict__ mw,
                        float* __restrict__ part) {
  int y = blockIdx.x, b = blockIdx.y, cg = blockIdx.z;
  int tx = threadIdx.x;      // 0..127
  float a0 = 0.f, a1 = 0.f, a2 = 0.f;
#pragma unroll
  for (int ci = 0; ci < 8; ++ci) {
    int c = cg * 8 + ci;
    const float* xp = x + ((size_t)(b * 64 + c)) * HW;
    const float* w0 = mw + (0 * 64 + c) * 9;
    const float* w1 = mw + (1 * 64 + c) * 9;
    const float* w2 = mw + (2 * 64 + c) * 9;
#pragma unroll
    for (int ky = 0; ky < 3; ++ky) {
      int yy = y + ky - 1;
      if ((unsigned)yy >= 128u) continue;
#pragma unroll
      for (int kx = 0; kx < 3; ++kx) {
        int xx = tx + kx - 1;
        if ((unsigned)xx >= 128u) continue;
        float xv = xp[yy * 128 + xx];
        a0 += xv * w0[ky * 3 + kx];
        a1 += xv * w1[ky * 3 + kx];
        a2 += xv * w2[ky * 3 + kx];
      }
    }
  }
  size_t base = (size_t)((b * 8 + cg) * 3) * HW + y * 128 + tx;
  part[base]          = a0;
  part[base + HW]     = a1;
  part[base + 2 * HW] = a2;
}

// -------- xm repack + FOLDED weight transforms + FOLDED mask softmax ---------
__global__ void k_xmt(const float* __restrict__ x, const float* __restrict__ part,
                      const float* __restrict__ mb, float* __restrict__ masks,
                      bf16* __restrict__ xm_p,
                      const float* __restrict__ kern, const float* __restrict__ w2,
                      bf16* __restrict__ kern_t, bf16* __restrict__ w2_t) {
  int yp = blockIdx.x;  // 0..141 padded row
  int m = blockIdx.y, b = blockIdx.z;
  int t = threadIdx.x;  // 256

  // ---- folded weight transforms: 1704 blocks x 256 thr x 2 iters -----------
  {
    const int NK  = 442368;            // kern_t elements
    const int NW2 = 147456;            // w2_t elements
    int bid2 = yp + 142 * (m + 3 * b); // 0..1703
#pragma unroll
    for (int it = 0; it < 2; ++it) {
      int idx = (bid2 + it * 1704) * 256 + t;
      if (idx < NK) {
        int j    = idx & 7;
        int lane = (idx >> 3) & 63;
        int km   = (idx >> 9) & 7;     // kci = km&1, mt = km>>1
        int tap  = (idx >> 12) % 9;
        int bm   = idx / 36864;
        int o = (km >> 1) * 16 + (lane & 15);
        int c = (km & 1) * 32 + (lane >> 4) * 8 + j;
        kern_t[idx] = (bf16)kern[(((bm * 64 + o) * 64 + c) * 9) + tap];
      } else if (idx < NK + NW2) {
        int j = idx - NK;
        int j8   = j & 7;
        int lane = (j >> 3) & 63;
        int km   = (j >> 9) & 7;
        int cq   = (j >> 12) & 3;
        int tap  = j >> 14;            // 0..8
        int oc = (km >> 1) * 16 + (lane & 15);
        int ch = cq * 64 + (km & 1) * 32 + (lane >> 4) * 8 + j8;
        w2_t[j] = (bf16)w2[(oc * 256 + ch) * 9 + tap];
      }
    }
  }

  bf16* prow = xm_p + (size_t)(b * 3 + m) * XM_PLANE + (size_t)yp * XM_ROW;
  bf16x8 z = {};
  if (yp < 7 || yp >= 135) {          // full halo row: 142*64/8 = 1136 chunks
#pragma unroll
    for (int i = 0; i < 5; ++i) {
      int u = i * 256 + t;
      if (u < 1136) ((bf16x8*)prow)[u] = z;
    }
    return;
  }
  // side halo: 7 px * 64c = 448 el = 56 chunks each side
  if (t < 56) ((bf16x8*)prow)[t] = z;
  else if (t < 112) ((bf16x8*)(prow + 135 * 64))[t - 56] = z;

  int y = yp - 7;
  __shared__ float tile[64 * 130];
  __shared__ float mrow_s[128];
#pragma unroll
  for (int i = 0; i < 32; ++i) {
    int u = i * 256 + t;           // 0..8191
    int c = u >> 7, xx = u & 127;
    tile[c * 130 + xx] = x[((size_t)(b * 64 + c)) * HW + y * 128 + xx];
  }
  // folded mask softmax: reduce 8 groups + bias + softmax (tx<128)
  if (t < 128) {
    float a0 = mb[0], a1 = mb[1], a2 = mb[2];
    int off = y * 128 + t;
#pragma unroll
    for (int cg = 0; cg < 8; ++cg) {
      size_t base = (size_t)((b * 8 + cg) * 3) * HW + off;
      a0 += part[base];
      a1 += part[base + HW];
      a2 += part[base + 2 * HW];
    }
    float mx = fmaxf(a0, fmaxf(a1, a2));
    float e0 = __expf(a0 - mx), e1 = __expf(a1 - mx), e2 = __expf(a2 - mx);
    float inv = 1.0f / (e0 + e1 + e2);
    float v0 = e0 * inv, v1 = e1 * inv, v2 = e2 * inv;
    mrow_s[t] = (m == 0) ? v0 : (m == 1) ? v1 : v2;
    if (m == 0) {                       // one writer per (y,b): all 3 rows
      size_t mbase = ((size_t)b * 3) * HW + off;
      masks[mbase]          = v0;
      masks[mbase + HW]     = v1;
      masks[mbase + 2 * HW] = v2;
    }
  }
  __syncthreads();
  bf16* orow = prow + 7 * 64;
  // vectorized repack: thread -> (cg = 8-ch group, xx = pixel); bf16x8 store
#pragma unroll
  for (int i = 0; i < 4; ++i) {
    int u = i * 256 + t;           // 0..1023
    int cg = u & 7, xx = u >> 3;
    float mv = mrow_s[xx];
    bf16x8 v;
#pragma unroll
    for (int j = 0; j < 8; ++j)
      v[j] = (bf16)(tile[(cg * 8 + j) * 130 + xx] * mv);
    *(bf16x8*)(orow + xx * 64 + cg * 8) = v;
  }
}

// ------- branch convs: wave-autonomous, 64px full-oc waves (2x A-intensity) --
// r18 showed the limiter is A-path L1 bandwidth (FETCH +50% when L1 sharing
// was lost). Waves widen 32->64 px at full 64 oc: same 24KB A per wave-phase
// now feeds 96 MFMA (was 48) -> per-CU A-traffic HALVES. 1024 blocks x 4
// waves; block = (b, d, y-pair); wave = (row, px-half). Private swizzled
// dbuf strip 78px = 19,968 B/wave (block 79,872 B -> 2 blocks/CU).
// Zero barriers, zero bank conflicts. Spill tripwire: WRITE_SIZE.
__global__ __launch_bounds__(256, 2) void k_branch(const bf16* __restrict__ xm_p,
                                                   const bf16* __restrict__ kern_t,
                                                   bf16* __restrict__ cat_p) {
  __shared__ bf16 sb[4][2][78 * 64];   // 4 waves x dbuf x 9,984 B = 79,872 B
  int bid = blockIdx.x;                // 0..1023
  // ---- folded halo zeroing: 66,048 items over 1024x256 threads -------------
  {
    int id = bid * 256 + threadIdx.x;
    if (id < 4 * 16512) {
      int plane = id / 16512, j = id % 16512;
      bf16* base = cat_p + (size_t)plane * CAT_PLANE;
      bf16x8 zv = {};
      if (j < 8320) {                   // rows 0 and 129, full 130 px
        int row = (j / 4160) * 129;
        int off = (j % 4160) * 8;
        *(bf16x8*)(base + (size_t)row * CAT_ROW + off) = zv;
      } else {                          // rows 1..128, cols 0 and 129
        int k = j - 8320;
        int row = 1 + (k >> 6);
        int idx2 = k & 63;
        int col = (idx2 >> 5) * 129;
        int ch8 = (idx2 & 31) * 8;
        *(bf16x8*)(base + (size_t)row * CAT_ROW + col * 256 + ch8) = zv;
      }
    }
  }
  int xcd = bid & 7;
  int i   = bid >> 3;          // 0..127
  int b   = xcd >> 1;
  int di  = ((xcd & 1) << 1) | (i & 1);
  int ypr = i >> 1;            // 0..63 (y pair)
  int d   = 1 + 2 * di;        // 1,3,5,7
  int t    = threadIdx.x;
  int lane = t & 63;
  int wave = t >> 6;           // 0..3
  int yr   = wave >> 1;        // row within pair
  int wh   = wave & 1;         // px half (64 px)
  int y    = ypr * 2 + yr;     // 0..127
  int lanelo = lane & 15;
  int quad = lane >> 4;

  const bf16* plane0 = xm_p + (size_t)(b * 3) * XM_PLANE;
  const bf16* wb0    = kern_t + (size_t)(b * 27) * 4096 + lane * 8;
  const int gp0 = wh * 64 + 7 - d;     // leftmost staged padded-px of this wave

  bf16* mysb0 = &sb[wave][0][0];
  bf16* mysb1 = &sb[wave][1][0];

  bf16x8 sreg[10];   // 78px x 64ch = 624 chunks of 16B (guard u<624)
  // swizzled LDS element offset for (px, slot): px*64 + ((slot ^ (px&7))<<3)
  // prologue: phase 0 (m=0,ky=0) -> buf0; issue phase 1 (m=0,ky=1) loads
  {
    const bf16* s0 = plane0 + (size_t)(y + 7 - d) * XM_ROW + gp0 * 64;
#pragma unroll
    for (int r = 0; r < 10; ++r) {
      int u = r * 64 + lane;
      if (u < 624) sreg[r] = *(const bf16x8*)(s0 + u * 8);
    }
#pragma unroll
    for (int r = 0; r < 10; ++r) {
      int u = r * 64 + lane;
      if (u < 624) {
        int px = u >> 3, sl = u & 7;
        *(bf16x8*)(mysb0 + px * 64 + ((sl ^ (px & 7)) << 3)) = sreg[r];
      }
    }
    const bf16* s1 = plane0 + (size_t)(y + 7) * XM_ROW + gp0 * 64;
#pragma unroll
    for (int r = 0; r < 10; ++r) {
      int u = r * 64 + lane;
      if (u < 624) sreg[r] = *(const bf16x8*)(s1 + u * 8);
    }
  }

  f32x4 acc[4][4] = {};

#pragma unroll
  for (int p = 0; p < 9; ++p) {
    int m = p / 3, ky = p % 3;
    // A-frags: 3 kx x 2 kci x 4 mt, each one coalesced 1KB wave-load
    bf16x8 areg[3][2][4];
    const bf16* wtap = wb0 + (size_t)(m * 9 + ky * 3) * 4096;
#pragma unroll
    for (int kx = 0; kx < 3; ++kx)
#pragma unroll
      for (int kci = 0; kci < 2; ++kci)
#pragma unroll
        for (int mt = 0; mt < 4; ++mt)
          areg[kx][kci][mt] = *(const bf16x8*)(wtap + kx * 4096 + (mt * 2 + kci) * 512);

    // write phase p+1 (loaded at p-1) into the other private buffer
    if (p < 8) {
      bf16* wbuf = ((p + 1) & 1) ? mysb1 : mysb0;
#pragma unroll
      for (int r = 0; r < 10; ++r) {
        int u = r * 64 + lane;
        if (u < 624) {
          int px = u >> 3, sl = u & 7;
          *(bf16x8*)(wbuf + px * 64 + ((sl ^ (px & 7)) << 3)) = sreg[r];
        }
      }
    }
    // issue staging loads for phase p+2
    if (p < 7) {
      int pn = p + 2;
      int mn = pn / 3, kyn = pn % 3;
      const bf16* sn = plane0 + (size_t)mn * XM_PLANE
                     + (size_t)(y + 7 + d * (kyn - 1)) * XM_ROW + gp0 * 64;
#pragma unroll
      for (int r = 0; r < 10; ++r) {
        int u = r * 64 + lane;
        if (u < 624) sreg[r] = *(const bf16x8*)(sn + u * 8);
      }
    }
    // compute from private buf[p&1]; local px = lanelo + d*kx (+ nt*16)
    const bf16* rbuf = (p & 1) ? mysb1 : mysb0;
#pragma unroll
    for (int kx = 0; kx < 3; ++kx) {
      int lpx0 = lanelo + d * kx;
      int p7   = lpx0 & 7;             // (lpx0+nt*16)&7 == lpx0&7
#pragma unroll
      for (int kci = 0; kci < 2; ++kci) {
        int swsl = ((quad + 4 * kci) ^ p7) << 3;
        bf16x8 bv[4];
#pragma unroll
        for (int nt = 0; nt < 4; ++nt)
          bv[nt] = *(const bf16x8*)(rbuf + (lpx0 + nt * 16) * 64 + swsl);
        __builtin_amdgcn_s_setprio(1);
#pragma unroll
        for (int mt = 0; mt < 4; ++mt)
#pragma unroll
          for (int nt = 0; nt < 4; ++nt)
            acc[mt][nt] = __builtin_amdgcn_mfma_f32_16x16x32_bf16(areg[kx][kci][mt], bv[nt], acc[mt][nt], 0, 0, 0);
        __builtin_amdgcn_s_setprio(0);
      }
    }
  }

  // epilogue: cat_p[b][y+1][px+1][di*64 + oc]
  bf16* cp = cat_p + (size_t)b * CAT_PLANE + (size_t)(y + 1) * CAT_ROW + di * 64;
#pragma unroll
  for (int mt = 0; mt < 4; ++mt) {
#pragma unroll
    for (int nt = 0; nt < 4; ++nt) {
      int px = wh * 64 + nt * 16 + lanelo;
      bf16x4 v;
#pragma unroll
      for (int r = 0; r < 4; ++r) v[r] = (bf16)acc[mt][nt][r];
      *(bf16x4*)(cp + (size_t)(px + 1) * 256 + (mt * 16 + quad * 4)) = v;
    }
  }
}

// ------- final conv + bias + BN + ReLU, v5: wave-autonomous (r17 form) -------
__global__ __launch_bounds__(256, 2) void k_final(const bf16* __restrict__ cat_p,
                                                  const bf16* __restrict__ w2_t,
                                                  const float* __restrict__ cb,
                                                  const float* __restrict__ gamma,
                                                  const float* __restrict__ beta,
                                                  const float* __restrict__ mean,
                                                  const float* __restrict__ var,
                                                  float* __restrict__ out) {
  __shared__ bf16 sb[4][2][40 * LPX];   // 4 waves x dbuf x 5,760 B = 46,080 B
  int bid = blockIdx.x;                 // 0..511
  int xcd = bid & 7;
  int b   = xcd >> 1;
  int y   = ((bid >> 3) << 1) | (xcd & 1);   // 0..127
  int t    = threadIdx.x;
  int lane = t & 63;
  int wq   = t >> 6;           // px quarter 0..3
  int lanelo = lane & 15;
  int quad = lane >> 4;

  const bf16* cb2 = cat_p + (size_t)b * CAT_PLANE + (size_t)(wq * 32) * 256;
  const bf16* wb0 = w2_t + lane * 8;

  bf16* mysb0 = &sb[wq][0][0];
  bf16* mysb1 = &sb[wq][1][0];

  bf16x8 sreg[5];   // 40px x 64ch = 320 chunks of 16B = 5 per lane
  // prologue: phase 0 (cq=0,ky=0) -> buf0; issue phase 1 (cq=0,ky=1) loads
  {
    const bf16* s0 = cb2 + (size_t)y * CAT_ROW;
#pragma unroll
    for (int r = 0; r < 5; ++r) {
      int u = r * 64 + lane;
      sreg[r] = *(const bf16x8*)(s0 + (u >> 3) * 256 + (u & 7) * 8);
    }
#pragma unroll
    for (int r = 0; r < 5; ++r) {
      int u = r * 64 + lane;
      *(bf16x8*)(mysb0 + (u >> 3) * LPX + (u & 7) * 8) = sreg[r];
    }
    const bf16* s1 = cb2 + (size_t)(y + 1) * CAT_ROW;
#pragma unroll
    for (int r = 0; r < 5; ++r) {
      int u = r * 64 + lane;
      sreg[r] = *(const bf16x8*)(s1 + (u >> 3) * 256 + (u & 7) * 8);
    }
  }

  f32x4 acc[4][2] = {};

#pragma unroll
  for (int p = 0; p < 12; ++p) {
    int cq = p / 3, ky = p % 3;
    // A-frags: 3 kx x 2 kci x 4 mt, each one coalesced 1KB wave-load
    bf16x8 areg[3][2][4];
#pragma unroll
    for (int kx = 0; kx < 3; ++kx) {
      const bf16* wt = wb0 + (size_t)(((ky * 3 + kx) * 4 + cq) * 8) * 512;
#pragma unroll
      for (int kci = 0; kci < 2; ++kci)
#pragma unroll
        for (int mt = 0; mt < 4; ++mt)
          areg[kx][kci][mt] = *(const bf16x8*)(wt + (mt * 2 + kci) * 512);
    }

    // write phase p+1 (loaded at p-1) into the other private buffer
    if (p < 11) {
      bf16* wbuf = ((p + 1) & 1) ? mysb1 : mysb0;
#pragma unroll
      for (int r = 0; r < 5; ++r) {
        int u = r * 64 + lane;
        *(bf16x8*)(wbuf + (u >> 3) * LPX + (u & 7) * 8) = sreg[r];
      }
    }
    // issue staging loads for phase p+2
    if (p < 10) {
      int pn = p + 2;
      int cqn = pn / 3, kyn = pn % 3;
      const bf16* sn = cb2 + (size_t)(y + kyn) * CAT_ROW + cqn * 64;
#pragma unroll
      for (int r = 0; r < 5; ++r) {
        int u = r * 64 + lane;
        sreg[r] = *(const bf16x8*)(sn + (u >> 3) * 256 + (u & 7) * 8);
      }
    }
    // compute from private buf[p&1]; local px = lanelo + kx (+ nt*16)
    const bf16* rbuf = (p & 1) ? mysb1 : mysb0;
#pragma unroll
    for (int kx = 0; kx < 3; ++kx) {
      int lpx0 = lanelo + kx;
#pragma unroll
      for (int kci = 0; kci < 2; ++kci) {
        bf16x8 bv[2];
#pragma unroll
        for (int nt = 0; nt < 2; ++nt)
          bv[nt] = *(const bf16x8*)(rbuf + (lpx0 + nt * 16) * LPX + quad * 8 + kci * 32);
        __builtin_amdgcn_s_setprio(1);
#pragma unroll
        for (int mt = 0; mt < 4; ++mt)
#pragma unroll
          for (int nt = 0; nt < 2; ++nt)
            acc[mt][nt] = __builtin_amdgcn_mfma_f32_16x16x32_bf16(areg[kx][kci][mt], bv[nt], acc[mt][nt], 0, 0, 0);
        __builtin_amdgcn_s_setprio(0);
      }
    }
  }

  // epilogue: bias + BN + ReLU -> out[b][oc][y][px]
#pragma unroll
  for (int mt = 0; mt < 4; ++mt) {
#pragma unroll
    for (int nt = 0; nt < 2; ++nt) {
      int px = wq * 32 + nt * 16 + lanelo;
#pragma unroll
      for (int r = 0; r < 4; ++r) {
        int oc = mt * 16 + quad * 4 + r;
        float inv = gamma[oc] * rsqrtf(var[oc] + 1e-5f);
        float v = (acc[mt][nt][r] + cb[oc]) * inv + beta[oc] - mean[oc] * inv;
        out[((size_t)(b * 64 + oc)) * HW + y * 128 + px] = fmaxf(v, 0.0f);
      }
    }
  }
}

extern "C" void kernel_launch(void* const* d_in, const int* in_sizes, int n_in,
                              void* d_out, int out_size, void* d_ws, size_t ws_size,
                              hipStream_t stream) {
  const float* x     = (const float*)d_in[0];
  const float* kern  = (const float*)d_in[1];
  const float* mw    = (const float*)d_in[2];
  const float* mb    = (const float*)d_in[3];
  const float* w2    = (const float*)d_in[4];
  const float* cb    = (const float*)d_in[5];
  const float* gamma = (const float*)d_in[6];
  const float* beta  = (const float*)d_in[7];
  const float* mean  = (const float*)d_in[8];
  const float* var   = (const float*)d_in[9];

  float* out   = (float*)d_out;
  float* masks = out + OUT_ELEMS;

  char* ws = (char*)d_ws;
  bf16* xm_p   = (bf16*)(ws);              // 30,971,904 B
  bf16* cat_p  = (bf16*)(ws + 30971904);   // 34,611,200 B (ends 65,583,104)
  bf16* kern_t = (bf16*)(ws + 65583104);   // 884,736 B
  bf16* w2_t   = (bf16*)(ws + 66467840);   // 294,912 B -> total 66,762,752 B
  // mask partials alias CAT_P region (dead before k_branch touches cat_p)
  float* part  = (float*)(ws + 30971904);  // 6,291,456 B < cat_p size

  k_mask1<<<dim3(128, 4, 8), 128, 0, stream>>>(x, mw, part);
  k_xmt<<<dim3(142, 3, 4), 256, 0, stream>>>(x, part, mb, masks, xm_p, kern, w2, kern_t, w2_t);
  k_branch<<<1024, 256, 0, stream>>>(xm_p, kern_t, cat_p);
  k_final<<<512, 256, 0, stream>>>(cat_p, w2_t, cb, gamma, beta, mean, var, out);
}

// Round 20
// 210.270 us; speedup vs baseline: 1.2323x; 1.0831x over previous
//
#include <hip/hip_runtime.h>
#include <math.h>

typedef __bf16 bf16;
typedef __bf16 bf16x8 __attribute__((ext_vector_type(8)));
typedef __bf16 bf16x4 __attribute__((ext_vector_type(4)));
typedef float  f32x4  __attribute__((ext_vector_type(4)));

#define HW        16384      // 128*128
#define OUT_ELEMS 4194304    // 4*64*128*128

// padded xm: [b][m][yp=142][xp=142][c=64], pixel (y,x) at (y+7, x+7)
#define XM_ROW    (142 * 64)
#define XM_PLANE  (142 * XM_ROW)          // 1,290,496 el
// padded cat: [b][yp=130][xp=130][ch=256], pixel (y,x) at (y+1, x+1)
#define CAT_ROW   (130 * 256)
#define CAT_PLANE (130 * CAT_ROW)         // 4,326,400 el

// LDS pixel stride for k_final (64 payload + 8 pad -> 144 B)
#define LPX 72

// -------- mask conv stage 1: partial logits over 8-channel groups ------------
// part aliases the cat_p region (dead before k_branch writes cat_p).
__global__ void k_mask1(const float* __restrict__ x, const float* __restrict__ mw,
                        float* __restrict__ part) {
  int y = blockIdx.x, b = blockIdx.y, cg = blockIdx.z;
  int tx = threadIdx.x;      // 0..127
  float a0 = 0.f, a1 = 0.f, a2 = 0.f;
#pragma unroll
  for (int ci = 0; ci < 8; ++ci) {
    int c = cg * 8 + ci;
    const float* xp = x + ((size_t)(b * 64 + c)) * HW;
    const float* w0 = mw + (0 * 64 + c) * 9;
    const float* w1 = mw + (1 * 64 + c) * 9;
    const float* w2 = mw + (2 * 64 + c) * 9;
#pragma unroll
    for (int ky = 0; ky < 3; ++ky) {
      int yy = y + ky - 1;
      if ((unsigned)yy >= 128u) continue;
#pragma unroll
      for (int kx = 0; kx < 3; ++kx) {
        int xx = tx + kx - 1;
        if ((unsigned)xx >= 128u) continue;
        float xv = xp[yy * 128 + xx];
        a0 += xv * w0[ky * 3 + kx];
        a1 += xv * w1[ky * 3 + kx];
        a2 += xv * w2[ky * 3 + kx];
      }
    }
  }
  size_t base = (size_t)((b * 8 + cg) * 3) * HW + y * 128 + tx;
  part[base]          = a0;
  part[base + HW]     = a1;
  part[base + 2 * HW] = a2;
}

// -------- xm repack + FOLDED weight transforms + FOLDED mask softmax ---------
__global__ void k_xmt(const float* __restrict__ x, const float* __restrict__ part,
                      const float* __restrict__ mb, float* __restrict__ masks,
                      bf16* __restrict__ xm_p,
                      const float* __restrict__ kern, const float* __restrict__ w2,
                      bf16* __restrict__ kern_t, bf16* __restrict__ w2_t) {
  int yp = blockIdx.x;  // 0..141 padded row
  int m = blockIdx.y, b = blockIdx.z;
  int t = threadIdx.x;  // 256

  // ---- folded weight transforms: 1704 blocks x 256 thr x 2 iters -----------
  {
    const int NK  = 442368;            // kern_t elements
    const int NW2 = 147456;            // w2_t elements
    int bid2 = yp + 142 * (m + 3 * b); // 0..1703
#pragma unroll
    for (int it = 0; it < 2; ++it) {
      int idx = (bid2 + it * 1704) * 256 + t;
      if (idx < NK) {
        int j    = idx & 7;
        int lane = (idx >> 3) & 63;
        int km   = (idx >> 9) & 7;     // kci = km&1, mt = km>>1
        int tap  = (idx >> 12) % 9;
        int bm   = idx / 36864;
        int o = (km >> 1) * 16 + (lane & 15);
        int c = (km & 1) * 32 + (lane >> 4) * 8 + j;
        kern_t[idx] = (bf16)kern[(((bm * 64 + o) * 64 + c) * 9) + tap];
      } else if (idx < NK + NW2) {
        int j = idx - NK;
        int j8   = j & 7;
        int lane = (j >> 3) & 63;
        int km   = (j >> 9) & 7;
        int cq   = (j >> 12) & 3;
        int tap  = j >> 14;            // 0..8
        int oc = (km >> 1) * 16 + (lane & 15);
        int ch = cq * 64 + (km & 1) * 32 + (lane >> 4) * 8 + j8;
        w2_t[j] = (bf16)w2[(oc * 256 + ch) * 9 + tap];
      }
    }
  }

  bf16* prow = xm_p + (size_t)(b * 3 + m) * XM_PLANE + (size_t)yp * XM_ROW;
  bf16x8 z = {};
  if (yp < 7 || yp >= 135) {          // full halo row: 142*64/8 = 1136 chunks
#pragma unroll
    for (int i = 0; i < 5; ++i) {
      int u = i * 256 + t;
      if (u < 1136) ((bf16x8*)prow)[u] = z;
    }
    return;
  }
  // side halo: 7 px * 64c = 448 el = 56 chunks each side
  if (t < 56) ((bf16x8*)prow)[t] = z;
  else if (t < 112) ((bf16x8*)(prow + 135 * 64))[t - 56] = z;

  int y = yp - 7;
  __shared__ float tile[64 * 130];
  __shared__ float mrow_s[128];
#pragma unroll
  for (int i = 0; i < 32; ++i) {
    int u = i * 256 + t;           // 0..8191
    int c = u >> 7, xx = u & 127;
    tile[c * 130 + xx] = x[((size_t)(b * 64 + c)) * HW + y * 128 + xx];
  }
  // folded mask softmax: reduce 8 groups + bias + softmax (tx<128)
  if (t < 128) {
    float a0 = mb[0], a1 = mb[1], a2 = mb[2];
    int off = y * 128 + t;
#pragma unroll
    for (int cg = 0; cg < 8; ++cg) {
      size_t base = (size_t)((b * 8 + cg) * 3) * HW + off;
      a0 += part[base];
      a1 += part[base + HW];
      a2 += part[base + 2 * HW];
    }
    float mx = fmaxf(a0, fmaxf(a1, a2));
    float e0 = __expf(a0 - mx), e1 = __expf(a1 - mx), e2 = __expf(a2 - mx);
    float inv = 1.0f / (e0 + e1 + e2);
    float v0 = e0 * inv, v1 = e1 * inv, v2 = e2 * inv;
    mrow_s[t] = (m == 0) ? v0 : (m == 1) ? v1 : v2;
    if (m == 0) {                       // one writer per (y,b): all 3 rows
      size_t mbase = ((size_t)b * 3) * HW + off;
      masks[mbase]          = v0;
      masks[mbase + HW]     = v1;
      masks[mbase + 2 * HW] = v2;
    }
  }
  __syncthreads();
  bf16* orow = prow + 7 * 64;
  // vectorized repack: thread -> (cg = 8-ch group, xx = pixel); bf16x8 store
#pragma unroll
  for (int i = 0; i < 4; ++i) {
    int u = i * 256 + t;           // 0..1023
    int cg = u & 7, xx = u >> 3;
    float mv = mrow_s[xx];
    bf16x8 v;
#pragma unroll
    for (int j = 0; j < 8; ++j)
      v[j] = (bf16)(tile[(cg * 8 + j) * 130 + xx] * mv);
    *(bf16x8*)(orow + xx * 64 + cg * 8) = v;
  }
}

// ------- branch convs: wave-autonomous, 64px full-oc waves, lean A-liveness --
// r19: widened waves won (81us) but spilled (~26MB scratch: WRITE +18.6MB).
// Fix: areg loads move INSIDE the kx loop (8 frags live, not 24) -> live set
// ~160 regs, no spill. L1-hit A-loads per kx overlap across 8 resident waves.
__global__ __launch_bounds__(256, 2) void k_branch(const bf16* __restrict__ xm_p,
                                                   const bf16* __restrict__ kern_t,
                                                   bf16* __restrict__ cat_p) {
  __shared__ bf16 sb[4][2][78 * 64];   // 4 waves x dbuf x 9,984 B = 79,872 B
  int bid = blockIdx.x;                // 0..1023
  // ---- folded halo zeroing: 66,048 items over 1024x256 threads -------------
  {
    int id = bid * 256 + threadIdx.x;
    if (id < 4 * 16512) {
      int plane = id / 16512, j = id % 16512;
      bf16* base = cat_p + (size_t)plane * CAT_PLANE;
      bf16x8 zv = {};
      if (j < 8320) {                   // rows 0 and 129, full 130 px
        int row = (j / 4160) * 129;
        int off = (j % 4160) * 8;
        *(bf16x8*)(base + (size_t)row * CAT_ROW + off) = zv;
      } else {                          // rows 1..128, cols 0 and 129
        int k = j - 8320;
        int row = 1 + (k >> 6);
        int idx2 = k & 63;
        int col = (idx2 >> 5) * 129;
        int ch8 = (idx2 & 31) * 8;
        *(bf16x8*)(base + (size_t)row * CAT_ROW + col * 256 + ch8) = zv;
      }
    }
  }
  int xcd = bid & 7;
  int i   = bid >> 3;          // 0..127
  int b   = xcd >> 1;
  int di  = ((xcd & 1) << 1) | (i & 1);
  int ypr = i >> 1;            // 0..63 (y pair)
  int d   = 1 + 2 * di;        // 1,3,5,7
  int t    = threadIdx.x;
  int lane = t & 63;
  int wave = t >> 6;           // 0..3
  int yr   = wave >> 1;        // row within pair
  int wh   = wave & 1;         // px half (64 px)
  int y    = ypr * 2 + yr;     // 0..127
  int lanelo = lane & 15;
  int quad = lane >> 4;

  const bf16* plane0 = xm_p + (size_t)(b * 3) * XM_PLANE;
  const bf16* wb0    = kern_t + (size_t)(b * 27) * 4096 + lane * 8;
  const int gp0 = wh * 64 + 7 - d;     // leftmost staged padded-px of this wave

  bf16* mysb0 = &sb[wave][0][0];
  bf16* mysb1 = &sb[wave][1][0];

  bf16x8 sreg[10];   // 78px x 64ch = 624 chunks of 16B (guard u<624)
  // swizzled LDS element offset for (px, slot): px*64 + ((slot ^ (px&7))<<3)
  // prologue: phase 0 (m=0,ky=0) -> buf0; issue phase 1 (m=0,ky=1) loads
  {
    const bf16* s0 = plane0 + (size_t)(y + 7 - d) * XM_ROW + gp0 * 64;
#pragma unroll
    for (int r = 0; r < 10; ++r) {
      int u = r * 64 + lane;
      if (u < 624) sreg[r] = *(const bf16x8*)(s0 + u * 8);
    }
#pragma unroll
    for (int r = 0; r < 10; ++r) {
      int u = r * 64 + lane;
      if (u < 624) {
        int px = u >> 3, sl = u & 7;
        *(bf16x8*)(mysb0 + px * 64 + ((sl ^ (px & 7)) << 3)) = sreg[r];
      }
    }
    const bf16* s1 = plane0 + (size_t)(y + 7) * XM_ROW + gp0 * 64;
#pragma unroll
    for (int r = 0; r < 10; ++r) {
      int u = r * 64 + lane;
      if (u < 624) sreg[r] = *(const bf16x8*)(s1 + u * 8);
    }
  }

  f32x4 acc[4][4] = {};

#pragma unroll
  for (int p = 0; p < 9; ++p) {
    int m = p / 3, ky = p % 3;
    const bf16* wtap = wb0 + (size_t)(m * 9 + ky * 3) * 4096;

    // write phase p+1 (loaded at p-1) into the other private buffer
    if (p < 8) {
      bf16* wbuf = ((p + 1) & 1) ? mysb1 : mysb0;
#pragma unroll
      for (int r = 0; r < 10; ++r) {
        int u = r * 64 + lane;
        if (u < 624) {
          int px = u >> 3, sl = u & 7;
          *(bf16x8*)(wbuf + px * 64 + ((sl ^ (px & 7)) << 3)) = sreg[r];
        }
      }
    }
    // issue staging loads for phase p+2
    if (p < 7) {
      int pn = p + 2;
      int mn = pn / 3, kyn = pn % 3;
      const bf16* sn = plane0 + (size_t)mn * XM_PLANE
                     + (size_t)(y + 7 + d * (kyn - 1)) * XM_ROW + gp0 * 64;
#pragma unroll
      for (int r = 0; r < 10; ++r) {
        int u = r * 64 + lane;
        if (u < 624) sreg[r] = *(const bf16x8*)(sn + u * 8);
      }
    }
    // compute from private buf[p&1]; A-frags loaded per-kx (8 live, no spill)
    const bf16* rbuf = (p & 1) ? mysb1 : mysb0;
#pragma unroll
    for (int kx = 0; kx < 3; ++kx) {
      bf16x8 areg[2][4];
#pragma unroll
      for (int kci = 0; kci < 2; ++kci)
#pragma unroll
        for (int mt = 0; mt < 4; ++mt)
          areg[kci][mt] = *(const bf16x8*)(wtap + kx * 4096 + (mt * 2 + kci) * 512);
      int lpx0 = lanelo + d * kx;
      int p7   = lpx0 & 7;             // (lpx0+nt*16)&7 == lpx0&7
#pragma unroll
      for (int kci = 0; kci < 2; ++kci) {
        int swsl = ((quad + 4 * kci) ^ p7) << 3;
        bf16x8 bv[4];
#pragma unroll
        for (int nt = 0; nt < 4; ++nt)
          bv[nt] = *(const bf16x8*)(rbuf + (lpx0 + nt * 16) * 64 + swsl);
        __builtin_amdgcn_s_setprio(1);
#pragma unroll
        for (int mt = 0; mt < 4; ++mt)
#pragma unroll
          for (int nt = 0; nt < 4; ++nt)
            acc[mt][nt] = __builtin_amdgcn_mfma_f32_16x16x32_bf16(areg[kci][mt], bv[nt], acc[mt][nt], 0, 0, 0);
        __builtin_amdgcn_s_setprio(0);
      }
    }
  }

  // epilogue: cat_p[b][y+1][px+1][di*64 + oc]
  bf16* cp = cat_p + (size_t)b * CAT_PLANE + (size_t)(y + 1) * CAT_ROW + di * 64;
#pragma unroll
  for (int mt = 0; mt < 4; ++mt) {
#pragma unroll
    for (int nt = 0; nt < 4; ++nt) {
      int px = wh * 64 + nt * 16 + lanelo;
      bf16x4 v;
#pragma unroll
      for (int r = 0; r < 4; ++r) v[r] = (bf16)acc[mt][nt][r];
      *(bf16x4*)(cp + (size_t)(px + 1) * 256 + (mt * 16 + quad * 4)) = v;
    }
  }
}

// ------- final conv + bias + BN + ReLU: 64px full-oc waves (2x A-intensity) --
// Ported r19's winning widening: 256 blocks x 4 waves; block = (b, y-pair);
// wave = (row, px-half) at full 64 oc (acc[4][4]). Private dbuf strip 66px
// (span 64+2) x LPX = 19,008 B/wave, block 76,032 B -> 2 blocks/CU.
// A-frags per-kx (8 live) from the start -- no spill.
__global__ __launch_bounds__(256, 2) void k_final(const bf16* __restrict__ cat_p,
                                                  const bf16* __restrict__ w2_t,
                                                  const float* __restrict__ cb,
                                                  const float* __restrict__ gamma,
                                                  const float* __restrict__ beta,
                                                  const float* __restrict__ mean,
                                                  const float* __restrict__ var,
                                                  float* __restrict__ out) {
  __shared__ bf16 sb[4][2][66 * LPX];   // 4 waves x dbuf x 9,504 B = 76,032 B
  int bid = blockIdx.x;                 // 0..255
  int xcd = bid & 7;
  int b   = xcd >> 1;
  int ypr = ((bid >> 3) << 1) | (xcd & 1);   // 0..63
  int t    = threadIdx.x;
  int lane = t & 63;
  int wave = t >> 6;
  int yr   = wave >> 1;        // row within pair
  int wh   = wave & 1;         // px half (64 px)
  int y    = ypr * 2 + yr;     // 0..127
  int lanelo = lane & 15;
  int quad = lane >> 4;

  const bf16* cb2 = cat_p + (size_t)b * CAT_PLANE + (size_t)(wh * 64) * 256;
  const bf16* wb0 = w2_t + lane * 8;

  bf16* mysb0 = &sb[wave][0][0];
  bf16* mysb1 = &sb[wave][1][0];

  bf16x8 sreg[9];   // 66px x 64ch = 528 chunks of 16B (guard u<528)
  // prologue: phase 0 (cq=0,ky=0) -> buf0; issue phase 1 (cq=0,ky=1) loads
  {
    const bf16* s0 = cb2 + (size_t)y * CAT_ROW;
#pragma unroll
    for (int r = 0; r < 9; ++r) {
      int u = r * 64 + lane;
      if (u < 528) sreg[r] = *(const bf16x8*)(s0 + (u >> 3) * 256 + (u & 7) * 8);
    }
#pragma unroll
    for (int r = 0; r < 9; ++r) {
      int u = r * 64 + lane;
      if (u < 528) *(bf16x8*)(mysb0 + (u >> 3) * LPX + (u & 7) * 8) = sreg[r];
    }
    const bf16* s1 = cb2 + (size_t)(y + 1) * CAT_ROW;
#pragma unroll
    for (int r = 0; r < 9; ++r) {
      int u = r * 64 + lane;
      if (u < 528) sreg[r] = *(const bf16x8*)(s1 + (u >> 3) * 256 + (u & 7) * 8);
    }
  }

  f32x4 acc[4][4] = {};

#pragma unroll
  for (int p = 0; p < 12; ++p) {
    int cq = p / 3, ky = p % 3;

    // write phase p+1 (loaded at p-1) into the other private buffer
    if (p < 11) {
      bf16* wbuf = ((p + 1) & 1) ? mysb1 : mysb0;
#pragma unroll
      for (int r = 0; r < 9; ++r) {
        int u = r * 64 + lane;
        if (u < 528) *(bf16x8*)(wbuf + (u >> 3) * LPX + (u & 7) * 8) = sreg[r];
      }
    }
    // issue staging loads for phase p+2
    if (p < 10) {
      int pn = p + 2;
      int cqn = pn / 3, kyn = pn % 3;
      const bf16* sn = cb2 + (size_t)(y + kyn) * CAT_ROW + cqn * 64;
#pragma unroll
      for (int r = 0; r < 9; ++r) {
        int u = r * 64 + lane;
        if (u < 528) sreg[r] = *(const bf16x8*)(sn + (u >> 3) * 256 + (u & 7) * 8);
      }
    }
    // compute from private buf[p&1]; A-frags per-kx
    const bf16* rbuf = (p & 1) ? mysb1 : mysb0;
#pragma unroll
    for (int kx = 0; kx < 3; ++kx) {
      bf16x8 areg[2][4];
      const bf16* wt = wb0 + (size_t)(((ky * 3 + kx) * 4 + cq) * 8) * 512;
#pragma unroll
      for (int kci = 0; kci < 2; ++kci)
#pragma unroll
        for (int mt = 0; mt < 4; ++mt)
          areg[kci][mt] = *(const bf16x8*)(wt + (mt * 2 + kci) * 512);
      int lpx0 = lanelo + kx;
#pragma unroll
      for (int kci = 0; kci < 2; ++kci) {
        bf16x8 bv[4];
#pragma unroll
        for (int nt = 0; nt < 4; ++nt)
          bv[nt] = *(const bf16x8*)(rbuf + (lpx0 + nt * 16) * LPX + quad * 8 + kci * 32);
        __builtin_amdgcn_s_setprio(1);
#pragma unroll
        for (int mt = 0; mt < 4; ++mt)
#pragma unroll
          for (int nt = 0; nt < 4; ++nt)
            acc[mt][nt] = __builtin_amdgcn_mfma_f32_16x16x32_bf16(areg[kci][mt], bv[nt], acc[mt][nt], 0, 0, 0);
        __builtin_amdgcn_s_setprio(0);
      }
    }
  }

  // epilogue: bias + BN + ReLU -> out[b][oc][y][px]
#pragma unroll
  for (int mt = 0; mt < 4; ++mt) {
#pragma unroll
    for (int nt = 0; nt < 4; ++nt) {
      int px = wh * 64 + nt * 16 + lanelo;
#pragma unroll
      for (int r = 0; r < 4; ++r) {
        int oc = mt * 16 + quad * 4 + r;
        float inv = gamma[oc] * rsqrtf(var[oc] + 1e-5f);
        float v = (acc[mt][nt][r] + cb[oc]) * inv + beta[oc] - mean[oc] * inv;
        out[((size_t)(b * 64 + oc)) * HW + y * 128 + px] = fmaxf(v, 0.0f);
      }
    }
  }
}

extern "C" void kernel_launch(void* const* d_in, const int* in_sizes, int n_in,
                              void* d_out, int out_size, void* d_ws, size_t ws_size,
                              hipStream_t stream) {
  const float* x     = (const float*)d_in[0];
  const float* kern  = (const float*)d_in[1];
  const float* mw    = (const float*)d_in[2];
  const float* mb    = (const float*)d_in[3];
  const float* w2    = (const float*)d_in[4];
  const float* cb    = (const float*)d_in[5];
  const float* gamma = (const float*)d_in[6];
  const float* beta  = (const float*)d_in[7];
  const float* mean  = (const float*)d_in[8];
  const float* var   = (const float*)d_in[9];

  float* out   = (float*)d_out;
  float* masks = out + OUT_ELEMS;

  char* ws = (char*)d_ws;
  bf16* xm_p   = (bf16*)(ws);              // 30,971,904 B
  bf16* cat_p  = (bf16*)(ws + 30971904);   // 34,611,200 B (ends 65,583,104)
  bf16* kern_t = (bf16*)(ws + 65583104);   // 884,736 B
  bf16* w2_t   = (bf16*)(ws + 66467840);   // 294,912 B -> total 66,762,752 B
  // mask partials alias CAT_P region (dead before k_branch touches cat_p)
  float* part  = (float*)(ws + 30971904);  // 6,291,456 B < cat_p size

  k_mask1<<<dim3(128, 4, 8), 128, 0, stream>>>(x, mw, part);
  k_xmt<<<dim3(142, 3, 4), 256, 0, stream>>>(x, part, mb, masks, xm_p, kern, w2, kern_t, w2_t);
  k_branch<<<1024, 256, 0, stream>>>(xm_p, kern_t, cat_p);
  k_final<<<256, 256, 0, stream>>>(cat_p, w2_t, cb, gamma, beta, mean, var, out);
}

// Round 21
// 208.668 us; speedup vs baseline: 1.2417x; 1.0077x over previous
//
#include <hip/hip_runtime.h>
#include <math.h>

typedef __bf16 bf16;
typedef __bf16 bf16x8 __attribute__((ext_vector_type(8)));
typedef __bf16 bf16x4 __attribute__((ext_vector_type(4)));
typedef float  f32x4  __attribute__((ext_vector_type(4)));

#define HW        16384      // 128*128
#define OUT_ELEMS 4194304    // 4*64*128*128

// padded xm: [b][m][yp=142][xp=142][c=64], pixel (y,x) at (y+7, x+7)
#define XM_ROW    (142 * 64)
#define XM_PLANE  (142 * XM_ROW)          // 1,290,496 el
// padded cat: [b][yp=130][xp=130][ch=256], pixel (y,x) at (y+1, x+1)
#define CAT_ROW   (130 * 256)
#define CAT_PLANE (130 * CAT_ROW)         // 4,326,400 el

// LDS pixel stride for k_final (64 payload + 8 pad -> 144 B)
#define LPX 72

// -------- mask conv stage 1: partial logits over 8-channel groups ------------
// part aliases the cat_p region (dead before k_branch writes cat_p).
__global__ void k_mask1(const float* __restrict__ x, const float* __restrict__ mw,
                        float* __restrict__ part) {
  int y = blockIdx.x, b = blockIdx.y, cg = blockIdx.z;
  int tx = threadIdx.x;      // 0..127
  float a0 = 0.f, a1 = 0.f, a2 = 0.f;
#pragma unroll
  for (int ci = 0; ci < 8; ++ci) {
    int c = cg * 8 + ci;
    const float* xp = x + ((size_t)(b * 64 + c)) * HW;
    const float* w0 = mw + (0 * 64 + c) * 9;
    const float* w1 = mw + (1 * 64 + c) * 9;
    const float* w2 = mw + (2 * 64 + c) * 9;
#pragma unroll
    for (int ky = 0; ky < 3; ++ky) {
      int yy = y + ky - 1;
      if ((unsigned)yy >= 128u) continue;
#pragma unroll
      for (int kx = 0; kx < 3; ++kx) {
        int xx = tx + kx - 1;
        if ((unsigned)xx >= 128u) continue;
        float xv = xp[yy * 128 + xx];
        a0 += xv * w0[ky * 3 + kx];
        a1 += xv * w1[ky * 3 + kx];
        a2 += xv * w2[ky * 3 + kx];
      }
    }
  }
  size_t base = (size_t)((b * 8 + cg) * 3) * HW + y * 128 + tx;
  part[base]          = a0;
  part[base + HW]     = a1;
  part[base + 2 * HW] = a2;
}

// -------- xm repack + FOLDED weight transforms + FOLDED mask softmax ---------
__global__ void k_xmt(const float* __restrict__ x, const float* __restrict__ part,
                      const float* __restrict__ mb, float* __restrict__ masks,
                      bf16* __restrict__ xm_p,
                      const float* __restrict__ kern, const float* __restrict__ w2,
                      bf16* __restrict__ kern_t, bf16* __restrict__ w2_t) {
  int yp = blockIdx.x;  // 0..141 padded row
  int m = blockIdx.y, b = blockIdx.z;
  int t = threadIdx.x;  // 256

  // ---- folded weight transforms: 1704 blocks x 256 thr x 2 iters -----------
  {
    const int NK  = 442368;            // kern_t elements
    const int NW2 = 147456;            // w2_t elements
    int bid2 = yp + 142 * (m + 3 * b); // 0..1703
#pragma unroll
    for (int it = 0; it < 2; ++it) {
      int idx = (bid2 + it * 1704) * 256 + t;
      if (idx < NK) {
        int j    = idx & 7;
        int lane = (idx >> 3) & 63;
        int km   = (idx >> 9) & 7;     // kci = km&1, mt = km>>1
        int tap  = (idx >> 12) % 9;
        int bm   = idx / 36864;
        int o = (km >> 1) * 16 + (lane & 15);
        int c = (km & 1) * 32 + (lane >> 4) * 8 + j;
        kern_t[idx] = (bf16)kern[(((bm * 64 + o) * 64 + c) * 9) + tap];
      } else if (idx < NK + NW2) {
        int j = idx - NK;
        int j8   = j & 7;
        int lane = (j >> 3) & 63;
        int km   = (j >> 9) & 7;
        int cq   = (j >> 12) & 3;
        int tap  = j >> 14;            // 0..8
        int oc = (km >> 1) * 16 + (lane & 15);
        int ch = cq * 64 + (km & 1) * 32 + (lane >> 4) * 8 + j8;
        w2_t[j] = (bf16)w2[(oc * 256 + ch) * 9 + tap];
      }
    }
  }

  bf16* prow = xm_p + (size_t)(b * 3 + m) * XM_PLANE + (size_t)yp * XM_ROW;
  bf16x8 z = {};
  if (yp < 7 || yp >= 135) {          // full halo row: 142*64/8 = 1136 chunks
#pragma unroll
    for (int i = 0; i < 5; ++i) {
      int u = i * 256 + t;
      if (u < 1136) ((bf16x8*)prow)[u] = z;
    }
    return;
  }
  // side halo: 7 px * 64c = 448 el = 56 chunks each side
  if (t < 56) ((bf16x8*)prow)[t] = z;
  else if (t < 112) ((bf16x8*)(prow + 135 * 64))[t - 56] = z;

  int y = yp - 7;
  __shared__ float tile[64 * 130];
  __shared__ float mrow_s[128];
#pragma unroll
  for (int i = 0; i < 32; ++i) {
    int u = i * 256 + t;           // 0..8191
    int c = u >> 7, xx = u & 127;
    tile[c * 130 + xx] = x[((size_t)(b * 64 + c)) * HW + y * 128 + xx];
  }
  // folded mask softmax: reduce 8 groups + bias + softmax (tx<128)
  if (t < 128) {
    float a0 = mb[0], a1 = mb[1], a2 = mb[2];
    int off = y * 128 + t;
#pragma unroll
    for (int cg = 0; cg < 8; ++cg) {
      size_t base = (size_t)((b * 8 + cg) * 3) * HW + off;
      a0 += part[base];
      a1 += part[base + HW];
      a2 += part[base + 2 * HW];
    }
    float mx = fmaxf(a0, fmaxf(a1, a2));
    float e0 = __expf(a0 - mx), e1 = __expf(a1 - mx), e2 = __expf(a2 - mx);
    float inv = 1.0f / (e0 + e1 + e2);
    float v0 = e0 * inv, v1 = e1 * inv, v2 = e2 * inv;
    mrow_s[t] = (m == 0) ? v0 : (m == 1) ? v1 : v2;
    if (m == 0) {                       // one writer per (y,b): all 3 rows
      size_t mbase = ((size_t)b * 3) * HW + off;
      masks[mbase]          = v0;
      masks[mbase + HW]     = v1;
      masks[mbase + 2 * HW] = v2;
    }
  }
  __syncthreads();
  bf16* orow = prow + 7 * 64;
  // vectorized repack: thread -> (cg = 8-ch group, xx = pixel); bf16x8 store
#pragma unroll
  for (int i = 0; i < 4; ++i) {
    int u = i * 256 + t;           // 0..1023
    int cg = u & 7, xx = u >> 3;
    float mv = mrow_s[xx];
    bf16x8 v;
#pragma unroll
    for (int j = 0; j < 8; ++j)
      v[j] = (bf16)(tile[(cg * 8 + j) * 130 + xx] * mv);
    *(bf16x8*)(orow + xx * 64 + cg * 8) = v;
  }
}

// ------- branch convs: wave-autonomous, 64px full-oc waves (r20 WIN: 66us) ---
__global__ __launch_bounds__(256, 2) void k_branch(const bf16* __restrict__ xm_p,
                                                   const bf16* __restrict__ kern_t,
                                                   bf16* __restrict__ cat_p) {
  __shared__ bf16 sb[4][2][78 * 64];   // 4 waves x dbuf x 9,984 B = 79,872 B
  int bid = blockIdx.x;                // 0..1023
  // ---- folded halo zeroing: 66,048 items over 1024x256 threads -------------
  {
    int id = bid * 256 + threadIdx.x;
    if (id < 4 * 16512) {
      int plane = id / 16512, j = id % 16512;
      bf16* base = cat_p + (size_t)plane * CAT_PLANE;
      bf16x8 zv = {};
      if (j < 8320) {                   // rows 0 and 129, full 130 px
        int row = (j / 4160) * 129;
        int off = (j % 4160) * 8;
        *(bf16x8*)(base + (size_t)row * CAT_ROW + off) = zv;
      } else {                          // rows 1..128, cols 0 and 129
        int k = j - 8320;
        int row = 1 + (k >> 6);
        int idx2 = k & 63;
        int col = (idx2 >> 5) * 129;
        int ch8 = (idx2 & 31) * 8;
        *(bf16x8*)(base + (size_t)row * CAT_ROW + col * 256 + ch8) = zv;
      }
    }
  }
  int xcd = bid & 7;
  int i   = bid >> 3;          // 0..127
  int b   = xcd >> 1;
  int di  = ((xcd & 1) << 1) | (i & 1);
  int ypr = i >> 1;            // 0..63 (y pair)
  int d   = 1 + 2 * di;        // 1,3,5,7
  int t    = threadIdx.x;
  int lane = t & 63;
  int wave = t >> 6;           // 0..3
  int yr   = wave >> 1;        // row within pair
  int wh   = wave & 1;         // px half (64 px)
  int y    = ypr * 2 + yr;     // 0..127
  int lanelo = lane & 15;
  int quad = lane >> 4;

  const bf16* plane0 = xm_p + (size_t)(b * 3) * XM_PLANE;
  const bf16* wb0    = kern_t + (size_t)(b * 27) * 4096 + lane * 8;
  const int gp0 = wh * 64 + 7 - d;     // leftmost staged padded-px of this wave

  bf16* mysb0 = &sb[wave][0][0];
  bf16* mysb1 = &sb[wave][1][0];

  bf16x8 sreg[10];   // 78px x 64ch = 624 chunks of 16B (guard u<624)
  // swizzled LDS element offset for (px, slot): px*64 + ((slot ^ (px&7))<<3)
  // prologue: phase 0 (m=0,ky=0) -> buf0; issue phase 1 (m=0,ky=1) loads
  {
    const bf16* s0 = plane0 + (size_t)(y + 7 - d) * XM_ROW + gp0 * 64;
#pragma unroll
    for (int r = 0; r < 10; ++r) {
      int u = r * 64 + lane;
      if (u < 624) sreg[r] = *(const bf16x8*)(s0 + u * 8);
    }
#pragma unroll
    for (int r = 0; r < 10; ++r) {
      int u = r * 64 + lane;
      if (u < 624) {
        int px = u >> 3, sl = u & 7;
        *(bf16x8*)(mysb0 + px * 64 + ((sl ^ (px & 7)) << 3)) = sreg[r];
      }
    }
    const bf16* s1 = plane0 + (size_t)(y + 7) * XM_ROW + gp0 * 64;
#pragma unroll
    for (int r = 0; r < 10; ++r) {
      int u = r * 64 + lane;
      if (u < 624) sreg[r] = *(const bf16x8*)(s1 + u * 8);
    }
  }

  f32x4 acc[4][4] = {};

#pragma unroll
  for (int p = 0; p < 9; ++p) {
    int m = p / 3, ky = p % 3;
    const bf16* wtap = wb0 + (size_t)(m * 9 + ky * 3) * 4096;

    // write phase p+1 (loaded at p-1) into the other private buffer
    if (p < 8) {
      bf16* wbuf = ((p + 1) & 1) ? mysb1 : mysb0;
#pragma unroll
      for (int r = 0; r < 10; ++r) {
        int u = r * 64 + lane;
        if (u < 624) {
          int px = u >> 3, sl = u & 7;
          *(bf16x8*)(wbuf + px * 64 + ((sl ^ (px & 7)) << 3)) = sreg[r];
        }
      }
    }
    // issue staging loads for phase p+2
    if (p < 7) {
      int pn = p + 2;
      int mn = pn / 3, kyn = pn % 3;
      const bf16* sn = plane0 + (size_t)mn * XM_PLANE
                     + (size_t)(y + 7 + d * (kyn - 1)) * XM_ROW + gp0 * 64;
#pragma unroll
      for (int r = 0; r < 10; ++r) {
        int u = r * 64 + lane;
        if (u < 624) sreg[r] = *(const bf16x8*)(sn + u * 8);
      }
    }
    // compute from private buf[p&1]; A-frags loaded per-kx (8 live, no spill)
    const bf16* rbuf = (p & 1) ? mysb1 : mysb0;
#pragma unroll
    for (int kx = 0; kx < 3; ++kx) {
      bf16x8 areg[2][4];
#pragma unroll
      for (int kci = 0; kci < 2; ++kci)
#pragma unroll
        for (int mt = 0; mt < 4; ++mt)
          areg[kci][mt] = *(const bf16x8*)(wtap + kx * 4096 + (mt * 2 + kci) * 512);
      int lpx0 = lanelo + d * kx;
      int p7   = lpx0 & 7;             // (lpx0+nt*16)&7 == lpx0&7
#pragma unroll
      for (int kci = 0; kci < 2; ++kci) {
        int swsl = ((quad + 4 * kci) ^ p7) << 3;
        bf16x8 bv[4];
#pragma unroll
        for (int nt = 0; nt < 4; ++nt)
          bv[nt] = *(const bf16x8*)(rbuf + (lpx0 + nt * 16) * 64 + swsl);
        __builtin_amdgcn_s_setprio(1);
#pragma unroll
        for (int mt = 0; mt < 4; ++mt)
#pragma unroll
          for (int nt = 0; nt < 4; ++nt)
            acc[mt][nt] = __builtin_amdgcn_mfma_f32_16x16x32_bf16(areg[kci][mt], bv[nt], acc[mt][nt], 0, 0, 0);
        __builtin_amdgcn_s_setprio(0);
      }
    }
  }

  // epilogue: cat_p[b][y+1][px+1][di*64 + oc]
  bf16* cp = cat_p + (size_t)b * CAT_PLANE + (size_t)(y + 1) * CAT_ROW + di * 64;
#pragma unroll
  for (int mt = 0; mt < 4; ++mt) {
#pragma unroll
    for (int nt = 0; nt < 4; ++nt) {
      int px = wh * 64 + nt * 16 + lanelo;
      bf16x4 v;
#pragma unroll
      for (int r = 0; r < 4; ++r) v[r] = (bf16)acc[mt][nt][r];
      *(bf16x4*)(cp + (size_t)(px + 1) * 256 + (mt * 16 + quad * 4)) = v;
    }
  }
}

// ------- final conv + bias + BN + ReLU, v7: K-SPLIT waves --------------------
// r20's 256-block k_final = 1 block/CU = 1 wave/SIMD: latency-naked. v7:
// 512 blocks (b, y); 4 waves = (wh = px-half) x (kq = K-half). Each wave
// keeps the 64px x 64oc shape (full A-intensity, acc[4][4], per-kx A) but
// does only cq in {2kq, 2kq+1}: 6 phases. End: kq=1 parks acc in its own
// (dead) LDS strip; one barrier; kq=0 adds + epilogue. 8 waves/CU.
__global__ __launch_bounds__(256, 2) void k_final(const bf16* __restrict__ cat_p,
                                                  const bf16* __restrict__ w2_t,
                                                  const float* __restrict__ cb,
                                                  const float* __restrict__ gamma,
                                                  const float* __restrict__ beta,
                                                  const float* __restrict__ mean,
                                                  const float* __restrict__ var,
                                                  float* __restrict__ out) {
  __shared__ bf16 sb[4][2][66 * LPX];   // 4 waves x dbuf x 9,504 B = 76,032 B
  int bid = blockIdx.x;                 // 0..511
  int xcd = bid & 7;
  int b   = xcd >> 1;
  int y   = ((bid >> 3) << 1) | (xcd & 1);   // 0..127
  int t    = threadIdx.x;
  int lane = t & 63;
  int wave = t >> 6;
  int wh   = wave & 1;         // px half (64 px)
  int kq   = wave >> 1;        // K half (cq pair)
  int lanelo = lane & 15;
  int quad = lane >> 4;

  const bf16* cb2 = cat_p + (size_t)b * CAT_PLANE + (size_t)(wh * 64) * 256;
  const bf16* wb0 = w2_t + lane * 8;

  bf16* mysb0 = &sb[wave][0][0];
  bf16* mysb1 = &sb[wave][1][0];

  bf16x8 sreg[9];   // 66px x 64ch = 528 chunks of 16B (guard u<528)
  // local phase p' in 0..5: cq = kq*2 + p'/3, ky = p'%3; src row y+ky
  // prologue: p'=0 -> buf0; issue p'=1 loads
  {
    const bf16* s0 = cb2 + (size_t)y * CAT_ROW + (kq * 2) * 64;
#pragma unroll
    for (int r = 0; r < 9; ++r) {
      int u = r * 64 + lane;
      if (u < 528) sreg[r] = *(const bf16x8*)(s0 + (u >> 3) * 256 + (u & 7) * 8);
    }
#pragma unroll
    for (int r = 0; r < 9; ++r) {
      int u = r * 64 + lane;
      if (u < 528) *(bf16x8*)(mysb0 + (u >> 3) * LPX + (u & 7) * 8) = sreg[r];
    }
    const bf16* s1 = cb2 + (size_t)(y + 1) * CAT_ROW + (kq * 2) * 64;
#pragma unroll
    for (int r = 0; r < 9; ++r) {
      int u = r * 64 + lane;
      if (u < 528) sreg[r] = *(const bf16x8*)(s1 + (u >> 3) * 256 + (u & 7) * 8);
    }
  }

  f32x4 acc[4][4] = {};

#pragma unroll
  for (int p = 0; p < 6; ++p) {
    int cq = kq * 2 + p / 3, ky = p % 3;

    // write phase p+1 (loaded at p-1) into the other private buffer
    if (p < 5) {
      bf16* wbuf = ((p + 1) & 1) ? mysb1 : mysb0;
#pragma unroll
      for (int r = 0; r < 9; ++r) {
        int u = r * 64 + lane;
        if (u < 528) *(bf16x8*)(wbuf + (u >> 3) * LPX + (u & 7) * 8) = sreg[r];
      }
    }
    // issue staging loads for phase p+2
    if (p < 4) {
      int pn = p + 2;
      int cqn = kq * 2 + pn / 3, kyn = pn % 3;
      const bf16* sn = cb2 + (size_t)(y + kyn) * CAT_ROW + cqn * 64;
#pragma unroll
      for (int r = 0; r < 9; ++r) {
        int u = r * 64 + lane;
        if (u < 528) sreg[r] = *(const bf16x8*)(sn + (u >> 3) * 256 + (u & 7) * 8);
      }
    }
    // compute from private buf[p&1]; A-frags per-kx
    const bf16* rbuf = (p & 1) ? mysb1 : mysb0;
#pragma unroll
    for (int kx = 0; kx < 3; ++kx) {
      bf16x8 areg[2][4];
      const bf16* wt = wb0 + (size_t)(((ky * 3 + kx) * 4 + cq) * 8) * 512;
#pragma unroll
      for (int kci = 0; kci < 2; ++kci)
#pragma unroll
        for (int mt = 0; mt < 4; ++mt)
          areg[kci][mt] = *(const bf16x8*)(wt + (mt * 2 + kci) * 512);
      int lpx0 = lanelo + kx;
#pragma unroll
      for (int kci = 0; kci < 2; ++kci) {
        bf16x8 bv[4];
#pragma unroll
        for (int nt = 0; nt < 4; ++nt)
          bv[nt] = *(const bf16x8*)(rbuf + (lpx0 + nt * 16) * LPX + quad * 8 + kci * 32);
        __builtin_amdgcn_s_setprio(1);
#pragma unroll
        for (int mt = 0; mt < 4; ++mt)
#pragma unroll
          for (int nt = 0; nt < 4; ++nt)
            acc[mt][nt] = __builtin_amdgcn_mfma_f32_16x16x32_bf16(areg[kci][mt], bv[nt], acc[mt][nt], 0, 0, 0);
        __builtin_amdgcn_s_setprio(0);
      }
    }
  }

  // K-reduction: kq=1 parks acc (16 f32/lane = 4KB) in its own dead strip
  if (kq == 1) {
    float* fs = (float*)mysb0;
#pragma unroll
    for (int mt = 0; mt < 4; ++mt)
#pragma unroll
      for (int nt = 0; nt < 4; ++nt)
#pragma unroll
        for (int r = 0; r < 4; ++r)
          fs[((mt * 4 + nt) * 4 + r) * 64 + lane] = acc[mt][nt][r];
  }
  asm volatile("s_waitcnt lgkmcnt(0)" ::: "memory");
  __builtin_amdgcn_s_barrier();
  __builtin_amdgcn_sched_barrier(0);
  if (kq == 1) return;

  // kq=0: add partner (wave^2) acc + bias/BN/ReLU epilogue
  const float* pf = (const float*)&sb[wave ^ 2][0][0];
#pragma unroll
  for (int mt = 0; mt < 4; ++mt) {
#pragma unroll
    for (int nt = 0; nt < 4; ++nt) {
      int px = wh * 64 + nt * 16 + lanelo;
#pragma unroll
      for (int r = 0; r < 4; ++r) {
        int oc = mt * 16 + quad * 4 + r;
        float s = acc[mt][nt][r] + pf[((mt * 4 + nt) * 4 + r) * 64 + lane];
        float inv = gamma[oc] * rsqrtf(var[oc] + 1e-5f);
        float v = (s + cb[oc]) * inv + beta[oc] - mean[oc] * inv;
        out[((size_t)(b * 64 + oc)) * HW + y * 128 + px] = fmaxf(v, 0.0f);
      }
    }
  }
}

extern "C" void kernel_launch(void* const* d_in, const int* in_sizes, int n_in,
                              void* d_out, int out_size, void* d_ws, size_t ws_size,
                              hipStream_t stream) {
  const float* x     = (const float*)d_in[0];
  const float* kern  = (const float*)d_in[1];
  const float* mw    = (const float*)d_in[2];
  const float* mb    = (const float*)d_in[3];
  const float* w2    = (const float*)d_in[4];
  const float* cb    = (const float*)d_in[5];
  const float* gamma = (const float*)d_in[6];
  const float* beta  = (const float*)d_in[7];
  const float* mean  = (const float*)d_in[8];
  const float* var   = (const float*)d_in[9];

  float* out   = (float*)d_out;
  float* masks = out + OUT_ELEMS;

  char* ws = (char*)d_ws;
  bf16* xm_p   = (bf16*)(ws);              // 30,971,904 B
  bf16* cat_p  = (bf16*)(ws + 30971904);   // 34,611,200 B (ends 65,583,104)
  bf16* kern_t = (bf16*)(ws + 65583104);   // 884,736 B
  bf16* w2_t   = (bf16*)(ws + 66467840);   // 294,912 B -> total 66,762,752 B
  // mask partials alias CAT_P region (dead before k_branch touches cat_p)
  float* part  = (float*)(ws + 30971904);  // 6,291,456 B < cat_p size

  k_mask1<<<dim3(128, 4, 8), 128, 0, stream>>>(x, mw, part);
  k_xmt<<<dim3(142, 3, 4), 256, 0, stream>>>(x, part, mb, masks, xm_p, kern, w2, kern_t, w2_t);
  k_branch<<<1024, 256, 0, stream>>>(xm_p, kern_t, cat_p);
  k_final<<<512, 256, 0, stream>>>(cat_p, w2_t, cb, gamma, beta, mean, var, out);
}

// Round 22
// 205.860 us; speedup vs baseline: 1.2587x; 1.0136x over previous
//
#include <hip/hip_runtime.h>
#include <math.h>

typedef __bf16 bf16;
typedef __bf16 bf16x8 __attribute__((ext_vector_type(8)));
typedef __bf16 bf16x4 __attribute__((ext_vector_type(4)));
typedef float  f32x4  __attribute__((ext_vector_type(4)));

#define HW        16384      // 128*128
#define OUT_ELEMS 4194304    // 4*64*128*128

// padded xm: [b][m][yp=142][xp=142][c=64], pixel (y,x) at (y+7, x+7)
#define XM_ROW    (142 * 64)
#define XM_PLANE  (142 * XM_ROW)          // 1,290,496 el
// padded cat: [b][yp=130][xp=130][ch=256], pixel (y,x) at (y+1, x+1)
#define CAT_ROW   (130 * 256)
#define CAT_PLANE (130 * CAT_ROW)         // 4,326,400 el

// LDS pixel stride for k_final (64 payload + 8 pad -> 144 B)
#define LPX 72

// -------- mask conv stage 1: partial logits over 8-channel groups ------------
// part aliases the cat_p region (dead before k_branch writes cat_p).
__global__ void k_mask1(const float* __restrict__ x, const float* __restrict__ mw,
                        float* __restrict__ part) {
  int y = blockIdx.x, b = blockIdx.y, cg = blockIdx.z;
  int tx = threadIdx.x;      // 0..127
  float a0 = 0.f, a1 = 0.f, a2 = 0.f;
#pragma unroll
  for (int ci = 0; ci < 8; ++ci) {
    int c = cg * 8 + ci;
    const float* xp = x + ((size_t)(b * 64 + c)) * HW;
    const float* w0 = mw + (0 * 64 + c) * 9;
    const float* w1 = mw + (1 * 64 + c) * 9;
    const float* w2 = mw + (2 * 64 + c) * 9;
#pragma unroll
    for (int ky = 0; ky < 3; ++ky) {
      int yy = y + ky - 1;
      if ((unsigned)yy >= 128u) continue;
#pragma unroll
      for (int kx = 0; kx < 3; ++kx) {
        int xx = tx + kx - 1;
        if ((unsigned)xx >= 128u) continue;
        float xv = xp[yy * 128 + xx];
        a0 += xv * w0[ky * 3 + kx];
        a1 += xv * w1[ky * 3 + kx];
        a2 += xv * w2[ky * 3 + kx];
      }
    }
  }
  size_t base = (size_t)((b * 8 + cg) * 3) * HW + y * 128 + tx;
  part[base]          = a0;
  part[base + HW]     = a1;
  part[base + 2 * HW] = a2;
}

// -------- xm repack v3: ONE block per (yp,b) handles all 3 m-planes ----------
// Old grid (yp,m,b) read the same 64x128 x-tile 3x (50MB instead of 16.8MB)
// and redid softmax 3x. Now: load tile once, softmax once (all 3 rows to
// LDS), repack 3 planes. Folded weight transforms re-spread (568 blk x 5 it).
__global__ void k_xmt(const float* __restrict__ x, const float* __restrict__ part,
                      const float* __restrict__ mb, float* __restrict__ masks,
                      bf16* __restrict__ xm_p,
                      const float* __restrict__ kern, const float* __restrict__ w2,
                      bf16* __restrict__ kern_t, bf16* __restrict__ w2_t) {
  int yp = blockIdx.x;  // 0..141 padded row
  int b  = blockIdx.y;  // 0..3
  int t  = threadIdx.x; // 256

  // ---- folded weight transforms: 568 blocks x 256 thr x 5 iters ------------
  {
    const int NK  = 442368;            // kern_t elements
    const int NW2 = 147456;            // w2_t elements
    int bid2 = yp + 142 * b;           // 0..567
#pragma unroll
    for (int it = 0; it < 5; ++it) {
      int idx = (bid2 + it * 568) * 256 + t;
      if (idx < NK) {
        int j    = idx & 7;
        int lane = (idx >> 3) & 63;
        int km   = (idx >> 9) & 7;     // kci = km&1, mt = km>>1
        int tap  = (idx >> 12) % 9;
        int bm   = idx / 36864;
        int o = (km >> 1) * 16 + (lane & 15);
        int c = (km & 1) * 32 + (lane >> 4) * 8 + j;
        kern_t[idx] = (bf16)kern[(((bm * 64 + o) * 64 + c) * 9) + tap];
      } else if (idx < NK + NW2) {
        int j = idx - NK;
        int j8   = j & 7;
        int lane = (j >> 3) & 63;
        int km   = (j >> 9) & 7;
        int cq   = (j >> 12) & 3;
        int tap  = j >> 14;            // 0..8
        int oc = (km >> 1) * 16 + (lane & 15);
        int ch = cq * 64 + (km & 1) * 32 + (lane >> 4) * 8 + j8;
        w2_t[j] = (bf16)w2[(oc * 256 + ch) * 9 + tap];
      }
    }
  }

  bf16x8 z = {};
  if (yp < 7 || yp >= 135) {          // full halo rows, 3 planes x 1136 chunks
#pragma unroll
    for (int i = 0; i < 14; ++i) {
      int u = i * 256 + t;
      if (u < 3408) {
        int m = u / 1136, c = u % 1136;
        bf16* prow = xm_p + (size_t)(b * 3 + m) * XM_PLANE + (size_t)yp * XM_ROW;
        ((bf16x8*)prow)[c] = z;
      }
    }
    return;
  }
  // side halos: 3 planes x 112 chunks = 336
#pragma unroll
  for (int i = 0; i < 2; ++i) {
    int u = i * 256 + t;
    if (u < 336) {
      int m = u / 112, off = u % 112;
      bf16* prow = xm_p + (size_t)(b * 3 + m) * XM_PLANE + (size_t)yp * XM_ROW;
      if (off < 56) ((bf16x8*)prow)[off] = z;
      else          ((bf16x8*)(prow + 135 * 64))[off - 56] = z;
    }
  }

  int y = yp - 7;
  __shared__ float tile[64 * 130];
  __shared__ float mrow_s[3][128];
#pragma unroll
  for (int i = 0; i < 32; ++i) {
    int u = i * 256 + t;           // 0..8191
    int c = u >> 7, xx = u & 127;
    tile[c * 130 + xx] = x[((size_t)(b * 64 + c)) * HW + y * 128 + xx];
  }
  // mask softmax once per (y,b): reduce 8 groups + bias + softmax (tx<128)
  if (t < 128) {
    float a0 = mb[0], a1 = mb[1], a2 = mb[2];
    int off = y * 128 + t;
#pragma unroll
    for (int cg = 0; cg < 8; ++cg) {
      size_t base = (size_t)((b * 8 + cg) * 3) * HW + off;
      a0 += part[base];
      a1 += part[base + HW];
      a2 += part[base + 2 * HW];
    }
    float mx = fmaxf(a0, fmaxf(a1, a2));
    float e0 = __expf(a0 - mx), e1 = __expf(a1 - mx), e2 = __expf(a2 - mx);
    float inv = 1.0f / (e0 + e1 + e2);
    float v0 = e0 * inv, v1 = e1 * inv, v2 = e2 * inv;
    mrow_s[0][t] = v0; mrow_s[1][t] = v1; mrow_s[2][t] = v2;
    size_t mbase = ((size_t)b * 3) * HW + off;
    masks[mbase]          = v0;
    masks[mbase + HW]     = v1;
    masks[mbase + 2 * HW] = v2;
  }
  __syncthreads();
  // repack 3 planes: 3 x 1024 chunks = 3072 over 256 thr = 12 iters
#pragma unroll
  for (int i = 0; i < 12; ++i) {
    int u = i * 256 + t;           // 0..3071
    int m  = u >> 10;              // 0..2
    int v2i = u & 1023;
    int cg = v2i & 7, xx = v2i >> 3;
    float mv = mrow_s[m][xx];
    bf16x8 vv;
#pragma unroll
    for (int j = 0; j < 8; ++j)
      vv[j] = (bf16)(tile[(cg * 8 + j) * 130 + xx] * mv);
    bf16* orow = xm_p + (size_t)(b * 3 + m) * XM_PLANE + (size_t)yp * XM_ROW + 7 * 64;
    *(bf16x8*)(orow + xx * 64 + cg * 8) = vv;
  }
}

// ------- branch convs: wave-autonomous, 64px full-oc waves (r20 WIN: 66us) ---
__global__ __launch_bounds__(256, 2) void k_branch(const bf16* __restrict__ xm_p,
                                                   const bf16* __restrict__ kern_t,
                                                   bf16* __restrict__ cat_p) {
  __shared__ bf16 sb[4][2][78 * 64];   // 4 waves x dbuf x 9,984 B = 79,872 B
  int bid = blockIdx.x;                // 0..1023
  // ---- folded halo zeroing: 66,048 items over 1024x256 threads -------------
  {
    int id = bid * 256 + threadIdx.x;
    if (id < 4 * 16512) {
      int plane = id / 16512, j = id % 16512;
      bf16* base = cat_p + (size_t)plane * CAT_PLANE;
      bf16x8 zv = {};
      if (j < 8320) {                   // rows 0 and 129, full 130 px
        int row = (j / 4160) * 129;
        int off = (j % 4160) * 8;
        *(bf16x8*)(base + (size_t)row * CAT_ROW + off) = zv;
      } else {                          // rows 1..128, cols 0 and 129
        int k = j - 8320;
        int row = 1 + (k >> 6);
        int idx2 = k & 63;
        int col = (idx2 >> 5) * 129;
        int ch8 = (idx2 & 31) * 8;
        *(bf16x8*)(base + (size_t)row * CAT_ROW + col * 256 + ch8) = zv;
      }
    }
  }
  int xcd = bid & 7;
  int i   = bid >> 3;          // 0..127
  int b   = xcd >> 1;
  int di  = ((xcd & 1) << 1) | (i & 1);
  int ypr = i >> 1;            // 0..63 (y pair)
  int d   = 1 + 2 * di;        // 1,3,5,7
  int t    = threadIdx.x;
  int lane = t & 63;
  int wave = t >> 6;           // 0..3
  int yr   = wave >> 1;        // row within pair
  int wh   = wave & 1;         // px half (64 px)
  int y    = ypr * 2 + yr;     // 0..127
  int lanelo = lane & 15;
  int quad = lane >> 4;

  const bf16* plane0 = xm_p + (size_t)(b * 3) * XM_PLANE;
  const bf16* wb0    = kern_t + (size_t)(b * 27) * 4096 + lane * 8;
  const int gp0 = wh * 64 + 7 - d;     // leftmost staged padded-px of this wave

  bf16* mysb0 = &sb[wave][0][0];
  bf16* mysb1 = &sb[wave][1][0];

  bf16x8 sreg[10];   // 78px x 64ch = 624 chunks of 16B (guard u<624)
  // swizzled LDS element offset for (px, slot): px*64 + ((slot ^ (px&7))<<3)
  // prologue: phase 0 (m=0,ky=0) -> buf0; issue phase 1 (m=0,ky=1) loads
  {
    const bf16* s0 = plane0 + (size_t)(y + 7 - d) * XM_ROW + gp0 * 64;
#pragma unroll
    for (int r = 0; r < 10; ++r) {
      int u = r * 64 + lane;
      if (u < 624) sreg[r] = *(const bf16x8*)(s0 + u * 8);
    }
#pragma unroll
    for (int r = 0; r < 10; ++r) {
      int u = r * 64 + lane;
      if (u < 624) {
        int px = u >> 3, sl = u & 7;
        *(bf16x8*)(mysb0 + px * 64 + ((sl ^ (px & 7)) << 3)) = sreg[r];
      }
    }
    const bf16* s1 = plane0 + (size_t)(y + 7) * XM_ROW + gp0 * 64;
#pragma unroll
    for (int r = 0; r < 10; ++r) {
      int u = r * 64 + lane;
      if (u < 624) sreg[r] = *(const bf16x8*)(s1 + u * 8);
    }
  }

  f32x4 acc[4][4] = {};

#pragma unroll
  for (int p = 0; p < 9; ++p) {
    int m = p / 3, ky = p % 3;
    const bf16* wtap = wb0 + (size_t)(m * 9 + ky * 3) * 4096;

    // write phase p+1 (loaded at p-1) into the other private buffer
    if (p < 8) {
      bf16* wbuf = ((p + 1) & 1) ? mysb1 : mysb0;
#pragma unroll
      for (int r = 0; r < 10; ++r) {
        int u = r * 64 + lane;
        if (u < 624) {
          int px = u >> 3, sl = u & 7;
          *(bf16x8*)(wbuf + px * 64 + ((sl ^ (px & 7)) << 3)) = sreg[r];
        }
      }
    }
    // issue staging loads for phase p+2
    if (p < 7) {
      int pn = p + 2;
      int mn = pn / 3, kyn = pn % 3;
      const bf16* sn = plane0 + (size_t)mn * XM_PLANE
                     + (size_t)(y + 7 + d * (kyn - 1)) * XM_ROW + gp0 * 64;
#pragma unroll
      for (int r = 0; r < 10; ++r) {
        int u = r * 64 + lane;
        if (u < 624) sreg[r] = *(const bf16x8*)(sn + u * 8);
      }
    }
    // compute from private buf[p&1]; A-frags loaded per-kx (8 live, no spill)
    const bf16* rbuf = (p & 1) ? mysb1 : mysb0;
#pragma unroll
    for (int kx = 0; kx < 3; ++kx) {
      bf16x8 areg[2][4];
#pragma unroll
      for (int kci = 0; kci < 2; ++kci)
#pragma unroll
        for (int mt = 0; mt < 4; ++mt)
          areg[kci][mt] = *(const bf16x8*)(wtap + kx * 4096 + (mt * 2 + kci) * 512);
      int lpx0 = lanelo + d * kx;
      int p7   = lpx0 & 7;             // (lpx0+nt*16)&7 == lpx0&7
#pragma unroll
      for (int kci = 0; kci < 2; ++kci) {
        int swsl = ((quad + 4 * kci) ^ p7) << 3;
        bf16x8 bv[4];
#pragma unroll
        for (int nt = 0; nt < 4; ++nt)
          bv[nt] = *(const bf16x8*)(rbuf + (lpx0 + nt * 16) * 64 + swsl);
        __builtin_amdgcn_s_setprio(1);
#pragma unroll
        for (int mt = 0; mt < 4; ++mt)
#pragma unroll
          for (int nt = 0; nt < 4; ++nt)
            acc[mt][nt] = __builtin_amdgcn_mfma_f32_16x16x32_bf16(areg[kci][mt], bv[nt], acc[mt][nt], 0, 0, 0);
        __builtin_amdgcn_s_setprio(0);
      }
    }
  }

  // epilogue: cat_p[b][y+1][px+1][di*64 + oc]
  bf16* cp = cat_p + (size_t)b * CAT_PLANE + (size_t)(y + 1) * CAT_ROW + di * 64;
#pragma unroll
  for (int mt = 0; mt < 4; ++mt) {
#pragma unroll
    for (int nt = 0; nt < 4; ++nt) {
      int px = wh * 64 + nt * 16 + lanelo;
      bf16x4 v;
#pragma unroll
      for (int r = 0; r < 4; ++r) v[r] = (bf16)acc[mt][nt][r];
      *(bf16x4*)(cp + (size_t)(px + 1) * 256 + (mt * 16 + quad * 4)) = v;
    }
  }
}

// ------- final conv + bias + BN + ReLU, v7: K-SPLIT waves (r21 form) ---------
__global__ __launch_bounds__(256, 2) void k_final(const bf16* __restrict__ cat_p,
                                                  const bf16* __restrict__ w2_t,
                                                  const float* __restrict__ cb,
                                                  const float* __restrict__ gamma,
                                                  const float* __restrict__ beta,
                                                  const float* __restrict__ mean,
                                                  const float* __restrict__ var,
                                                  float* __restrict__ out) {
  __shared__ bf16 sb[4][2][66 * LPX];   // 4 waves x dbuf x 9,504 B = 76,032 B
  int bid = blockIdx.x;                 // 0..511
  int xcd = bid & 7;
  int b   = xcd >> 1;
  int y   = ((bid >> 3) << 1) | (xcd & 1);   // 0..127
  int t    = threadIdx.x;
  int lane = t & 63;
  int wave = t >> 6;
  int wh   = wave & 1;         // px half (64 px)
  int kq   = wave >> 1;        // K half (cq pair)
  int lanelo = lane & 15;
  int quad = lane >> 4;

  const bf16* cb2 = cat_p + (size_t)b * CAT_PLANE + (size_t)(wh * 64) * 256;
  const bf16* wb0 = w2_t + lane * 8;

  bf16* mysb0 = &sb[wave][0][0];
  bf16* mysb1 = &sb[wave][1][0];

  bf16x8 sreg[9];   // 66px x 64ch = 528 chunks of 16B (guard u<528)
  // local phase p' in 0..5: cq = kq*2 + p'/3, ky = p'%3; src row y+ky
  {
    const bf16* s0 = cb2 + (size_t)y * CAT_ROW + (kq * 2) * 64;
#pragma unroll
    for (int r = 0; r < 9; ++r) {
      int u = r * 64 + lane;
      if (u < 528) sreg[r] = *(const bf16x8*)(s0 + (u >> 3) * 256 + (u & 7) * 8);
    }
#pragma unroll
    for (int r = 0; r < 9; ++r) {
      int u = r * 64 + lane;
      if (u < 528) *(bf16x8*)(mysb0 + (u >> 3) * LPX + (u & 7) * 8) = sreg[r];
    }
    const bf16* s1 = cb2 + (size_t)(y + 1) * CAT_ROW + (kq * 2) * 64;
#pragma unroll
    for (int r = 0; r < 9; ++r) {
      int u = r * 64 + lane;
      if (u < 528) sreg[r] = *(const bf16x8*)(s1 + (u >> 3) * 256 + (u & 7) * 8);
    }
  }

  f32x4 acc[4][4] = {};

#pragma unroll
  for (int p = 0; p < 6; ++p) {
    int cq = kq * 2 + p / 3, ky = p % 3;

    if (p < 5) {
      bf16* wbuf = ((p + 1) & 1) ? mysb1 : mysb0;
#pragma unroll
      for (int r = 0; r < 9; ++r) {
        int u = r * 64 + lane;
        if (u < 528) *(bf16x8*)(wbuf + (u >> 3) * LPX + (u & 7) * 8) = sreg[r];
      }
    }
    if (p < 4) {
      int pn = p + 2;
      int cqn = kq * 2 + pn / 3, kyn = pn % 3;
      const bf16* sn = cb2 + (size_t)(y + kyn) * CAT_ROW + cqn * 64;
#pragma unroll
      for (int r = 0; r < 9; ++r) {
        int u = r * 64 + lane;
        if (u < 528) sreg[r] = *(const bf16x8*)(sn + (u >> 3) * 256 + (u & 7) * 8);
      }
    }
    const bf16* rbuf = (p & 1) ? mysb1 : mysb0;
#pragma unroll
    for (int kx = 0; kx < 3; ++kx) {
      bf16x8 areg[2][4];
      const bf16* wt = wb0 + (size_t)(((ky * 3 + kx) * 4 + cq) * 8) * 512;
#pragma unroll
      for (int kci = 0; kci < 2; ++kci)
#pragma unroll
        for (int mt = 0; mt < 4; ++mt)
          areg[kci][mt] = *(const bf16x8*)(wt + (mt * 2 + kci) * 512);
      int lpx0 = lanelo + kx;
#pragma unroll
      for (int kci = 0; kci < 2; ++kci) {
        bf16x8 bv[4];
#pragma unroll
        for (int nt = 0; nt < 4; ++nt)
          bv[nt] = *(const bf16x8*)(rbuf + (lpx0 + nt * 16) * LPX + quad * 8 + kci * 32);
        __builtin_amdgcn_s_setprio(1);
#pragma unroll
        for (int mt = 0; mt < 4; ++mt)
#pragma unroll
          for (int nt = 0; nt < 4; ++nt)
            acc[mt][nt] = __builtin_amdgcn_mfma_f32_16x16x32_bf16(areg[kci][mt], bv[nt], acc[mt][nt], 0, 0, 0);
        __builtin_amdgcn_s_setprio(0);
      }
    }
  }

  // K-reduction: kq=1 parks acc (16 f32/lane = 4KB) in its own dead strip
  if (kq == 1) {
    float* fs = (float*)mysb0;
#pragma unroll
    for (int mt = 0; mt < 4; ++mt)
#pragma unroll
      for (int nt = 0; nt < 4; ++nt)
#pragma unroll
        for (int r = 0; r < 4; ++r)
          fs[((mt * 4 + nt) * 4 + r) * 64 + lane] = acc[mt][nt][r];
  }
  asm volatile("s_waitcnt lgkmcnt(0)" ::: "memory");
  __builtin_amdgcn_s_barrier();
  __builtin_amdgcn_sched_barrier(0);
  if (kq == 1) return;

  // kq=0: add partner (wave^2) acc + bias/BN/ReLU epilogue
  const float* pf = (const float*)&sb[wave ^ 2][0][0];
#pragma unroll
  for (int mt = 0; mt < 4; ++mt) {
#pragma unroll
    for (int nt = 0; nt < 4; ++nt) {
      int px = wh * 64 + nt * 16 + lanelo;
#pragma unroll
      for (int r = 0; r < 4; ++r) {
        int oc = mt * 16 + quad * 4 + r;
        float s = acc[mt][nt][r] + pf[((mt * 4 + nt) * 4 + r) * 64 + lane];
        float inv = gamma[oc] * rsqrtf(var[oc] + 1e-5f);
        float v = (s + cb[oc]) * inv + beta[oc] - mean[oc] * inv;
        out[((size_t)(b * 64 + oc)) * HW + y * 128 + px] = fmaxf(v, 0.0f);
      }
    }
  }
}

extern "C" void kernel_launch(void* const* d_in, const int* in_sizes, int n_in,
                              void* d_out, int out_size, void* d_ws, size_t ws_size,
                              hipStream_t stream) {
  const float* x     = (const float*)d_in[0];
  const float* kern  = (const float*)d_in[1];
  const float* mw    = (const float*)d_in[2];
  const float* mb    = (const float*)d_in[3];
  const float* w2    = (const float*)d_in[4];
  const float* cb    = (const float*)d_in[5];
  const float* gamma = (const float*)d_in[6];
  const float* beta  = (const float*)d_in[7];
  const float* mean  = (const float*)d_in[8];
  const float* var   = (const float*)d_in[9];

  float* out   = (float*)d_out;
  float* masks = out + OUT_ELEMS;

  char* ws = (char*)d_ws;
  bf16* xm_p   = (bf16*)(ws);              // 30,971,904 B
  bf16* cat_p  = (bf16*)(ws + 30971904);   // 34,611,200 B (ends 65,583,104)
  bf16* kern_t = (bf16*)(ws + 65583104);   // 884,736 B
  bf16* w2_t   = (bf16*)(ws + 66467840);   // 294,912 B -> total 66,762,752 B
  // mask partials alias CAT_P region (dead before k_branch touches cat_p)
  float* part  = (float*)(ws + 30971904);  // 6,291,456 B < cat_p size

  k_mask1<<<dim3(128, 4, 8), 128, 0, stream>>>(x, mw, part);
  k_xmt<<<dim3(142, 4), 256, 0, stream>>>(x, part, mb, masks, xm_p, kern, w2, kern_t, w2_t);
  k_branch<<<1024, 256, 0, stream>>>(xm_p, kern_t, cat_p);
  k_final<<<512, 256, 0, stream>>>(cat_p, w2_t, cb, gamma, beta, mean, var, out);
}